// Round 2
// baseline (9325.978 us; speedup 1.0000x reference)
//
#include <hip/hip_runtime.h>
#include <hip/hip_bf16.h>

#define NN 20000
#define NE 320000

// jax.nn.gelu default (approximate=True): 0.5x(1+tanh(t)) == x*sigmoid(2t)
__device__ __forceinline__ float geluf(float x){
  float t = 0.7978845608028654f * x * (1.0f + 0.044715f * x * x);
  return x / (1.0f + __expf(-2.0f * t));
}

// ---------------- weight transpose/copy (fp32 -> fp32 in ws) ----------------
struct TEnt { const float* src; float* dst; int R; int C; int trans; };
struct TTab { TEnt e[26]; };

__global__ void convw(TTab t){
  TEnt en = t.e[blockIdx.x];
  int n = en.R * en.C;
  for (int i = threadIdx.x; i < n; i += blockDim.x){
    float v = en.src[i];
    if (en.trans){
      int r = i / en.C, c = i - r * en.C;
      en.dst[c * en.R + r] = v;          // dst[C][R]
    } else {
      en.dst[i] = v;
    }
  }
}

// ---------------- node init: xn[:,0:32] = mlp2(embed[z]), zero rest ---------
__global__ __launch_bounds__(256) void node_init(
    const int* __restrict__ az, const float* __restrict__ embedF,
    const float* __restrict__ w1T /*[32][8]*/, const float* __restrict__ w2T /*[32][32]*/,
    float* __restrict__ xn)
{
  int n = blockIdx.x * 256 + threadIdx.x;
  if (n >= NN) return;
  int z = az[n];
  float ee[8];
#pragma unroll
  for (int k = 0; k < 8; k++) ee[k] = embedF[z * 8 + k];
  float hid[32];
#pragma unroll
  for (int l = 0; l < 32; l++){
    float a = 0.f;
#pragma unroll
    for (int k = 0; k < 8; k++) a += ee[k] * w1T[l * 8 + k];
    hid[l] = geluf(a);
  }
  float* row = xn + (long)n * 96;
#pragma unroll
  for (int j = 0; j < 32; j++){
    float a = 0.f;
#pragma unroll
    for (int l = 0; l < 32; l++) a += hid[l] * w2T[j * 32 + l];
    row[j] = a;
  }
#pragma unroll
  for (int j = 32; j < 96; j++) row[j] = 0.f;
}

// ---------------- edge init: basis store + xe mlp + W0/W1 scatter -----------
__global__ __launch_bounds__(256) void edge_init(
    const float* __restrict__ pos, const int* __restrict__ esrc, const int* __restrict__ edst,
    float* __restrict__ basis, float* __restrict__ xn,
    const float* __restrict__ w1T /*dl1w1T [32][4]*/, const float* __restrict__ w2T /*[32][32]*/,
    const float* __restrict__ f1T /*[2][64][10]*/, const float* __restrict__ f2T /*[2][32][64]*/)
{
  int e = blockIdx.x * 256 + threadIdx.x;
  if (e >= NE) return;
  int s = esrc[e], d = edst[e];
  float vx = pos[s*3+0] - pos[d*3+0];
  float vy = pos[s*3+1] - pos[d*3+1];
  float vz = pos[s*3+2] - pos[d*3+2];
  float len = sqrtf(vx*vx + vy*vy + vz*vz + 1e-12f);
  float rs  = fmaxf(len, 1e-6f);
  float inv = 1.0f / rs;
  float b[10];
#pragma unroll
  for (int k = 0; k < 10; k++){
    b[k] = sinf(3.14159265358979323f * (float)(k+1) * 0.5f * len) * inv * 3.1622776601683795f;
    basis[k * NE + e] = b[k];
  }
  float u = len - 2.0f;   // 2*(len/MAXR - 1), MAXR=2
  float cut = 0.5f * (1.0f - cosf(3.14159265358979323f * u));
  cut = (u > 0.0f) ? 0.0f : cut;
  cut = (u < -1.0f) ? 1.0f : cut;
  float xe0 = cut, cc = cut * 1.7320508075688772f * inv;
  float xe1 = cc*vx, xe2 = cc*vy, xe3 = cc*vz;
  float hid[32];
#pragma unroll
  for (int l = 0; l < 32; l++){
    float a = xe0*w1T[l*4+0] + xe1*w1T[l*4+1] + xe2*w1T[l*4+2] + xe3*w1T[l*4+3];
    hid[l] = geluf(a);
  }
  float xeh[32];
#pragma unroll
  for (int j = 0; j < 32; j++){
    float a = 0.f;
#pragma unroll
    for (int l = 0; l < 32; l++) a += hid[l] * w2T[j*32 + l];
    xeh[j] = a;
  }
  float* xdrow = xn + (long)d * 96;
  float* xsrow = xn + (long)s * 96;
  float h64[64];
#pragma unroll
  for (int l = 0; l < 64; l++){
    float a = 0.f;
#pragma unroll
    for (int k = 0; k < 10; k++) a += b[k] * f1T[l*10 + k];
    h64[l] = geluf(a);
  }
  for (int j = 0; j < 32; j++){
    float a = 0.f;
#pragma unroll
    for (int l = 0; l < 64; l++) a += h64[l] * f2T[j*64 + l];
    float v = a * xeh[j];
    unsafeAtomicAdd(xdrow + 32 + j,  v);
    unsafeAtomicAdd(xsrow + 32 + j, -v);
  }
#pragma unroll
  for (int l = 0; l < 64; l++){
    float a = 0.f;
#pragma unroll
    for (int k = 0; k < 10; k++) a += b[k] * f1T[640 + l*10 + k];
    h64[l] = geluf(a);
  }
  for (int j = 0; j < 32; j++){
    float a = 0.f;
#pragma unroll
    for (int l = 0; l < 64; l++) a += h64[l] * f2T[2048 + j*64 + l];
    float v = 0.5f * a * xeh[j];
    unsafeAtomicAdd(xdrow + 64 + j, v);
    unsafeAtomicAdd(xsrow + 64 + j, v);
  }
}

// ---------------- conv layer: the heavy per-edge kernel ---------------------
__global__ __launch_bounds__(256) void layer_k(
    const float* __restrict__ basis, const int* __restrict__ esrc,
    const int* __restrict__ edst, const float* __restrict__ xn,
    float* __restrict__ delta,
    const float* __restrict__ w1aT, const float* __restrict__ w1bT,
    const float* __restrict__ w1cT, const float* __restrict__ w2aT,
    const float* __restrict__ w2bT, const float* __restrict__ w2cT,
    const float* __restrict__ dw1,  const float* __restrict__ dw2T)
{
  int e = blockIdx.x * 256 + threadIdx.x;
  if (e >= NE) return;
  int s = esrc[e], d = edst[e];
  float b[10];
#pragma unroll
  for (int k = 0; k < 10; k++) b[k] = basis[k * NE + e];
  const float* xsr = xn + (long)s * 96;
  const float* xdr = xn + (long)d * 96;
  float h[64];
  float hd[32];
#pragma unroll
  for (int l = 0; l < 32; l++) hd[l] = 0.f;

  // ---- pass A: hA = gelu(b@w1a); accumulate grad-part into hd ----
#pragma unroll
  for (int l = 0; l < 64; l++){
    float a = 0.f;
#pragma unroll
    for (int k = 0; k < 10; k++) a += b[k] * w1aT[l*10 + k];
    h[l] = geluf(a);
  }
  for (int jc = 0; jc < 96; jc += 8){
    float4 t0 = *(const float4*)(xsr + jc);
    float4 t1 = *(const float4*)(xsr + jc + 4);
    float4 u0 = *(const float4*)(xdr + jc);
    float4 u1 = *(const float4*)(xdr + jc + 4);
    float xs[8] = {t0.x,t0.y,t0.z,t0.w,t1.x,t1.y,t1.z,t1.w};
    float xd[8] = {u0.x,u0.y,u0.z,u0.w,u1.x,u1.y,u1.z,u1.w};
#pragma unroll
    for (int j = 0; j < 8; j++){
      float a = 0.f;
#pragma unroll
      for (int l = 0; l < 64; l++) a += h[l] * w2aT[(jc+j)*64 + l];
      float g = a * (xd[j] - xs[j]);
#pragma unroll
      for (int l = 0; l < 32; l++) hd[l] += g * dw1[(jc+j)*32 + l];
    }
  }
  // ---- pass B: hB; accumulate ave-part into hd ----
#pragma unroll
  for (int l = 0; l < 64; l++){
    float a = 0.f;
#pragma unroll
    for (int k = 0; k < 10; k++) a += b[k] * w1bT[l*10 + k];
    h[l] = geluf(a);
  }
  for (int jc = 0; jc < 96; jc += 8){
    float4 t0 = *(const float4*)(xsr + jc);
    float4 t1 = *(const float4*)(xsr + jc + 4);
    float4 u0 = *(const float4*)(xdr + jc);
    float4 u1 = *(const float4*)(xdr + jc + 4);
    float xs[8] = {t0.x,t0.y,t0.z,t0.w,t1.x,t1.y,t1.z,t1.w};
    float xd[8] = {u0.x,u0.y,u0.z,u0.w,u1.x,u1.y,u1.z,u1.w};
#pragma unroll
    for (int j = 0; j < 8; j++){
      float a = 0.f;
#pragma unroll
      for (int l = 0; l < 64; l++) a += h[l] * w2bT[(jc+j)*64 + l];
      float g = a * 0.5f * (xd[j] + xs[j]);
#pragma unroll
      for (int l = 0; l < 32; l++) hd[l] += g * dw1[(96+jc+j)*32 + l];
    }
  }
#pragma unroll
  for (int l = 0; l < 32; l++) hd[l] = geluf(hd[l]);
  // ---- hC ----
#pragma unroll
  for (int l = 0; l < 64; l++){
    float a = 0.f;
#pragma unroll
    for (int k = 0; k < 10; k++) a += b[k] * w1cT[l*10 + k];
    h[l] = geluf(a);
  }
  // ---- output: dxe = hd@dw2, Wc = hC@w2c, fused div+ave scatter ----
  float* dd = delta + (long)d * 96;
  float* ds = delta + (long)s * 96;
  for (int j = 0; j < 96; j++){
    float d1 = 0.f, d2 = 0.f, c1 = 0.f, c2 = 0.f;
#pragma unroll
    for (int l = 0; l < 32; l++){
      d1 += hd[l] * dw2T[j*32 + l];
      d2 += hd[l] * dw2T[(96+j)*32 + l];
    }
#pragma unroll
    for (int l = 0; l < 64; l++){
      c1 += h[l] * w2cT[j*64 + l];
      c2 += h[l] * w2cT[(96+j)*64 + l];
    }
    float dv = c1 * d1, av = 0.5f * c2 * d2;
    unsafeAtomicAdd(dd + j, dv + av);
    unsafeAtomicAdd(ds + j, av - dv);
  }
}

// ---------------- xn -= h*delta; re-zero delta ------------------------------
__global__ void node_upd(float* __restrict__ xn, float* __restrict__ delta){
  int i = blockIdx.x * 256 + threadIdx.x;
  if (i < NN * 96){
    xn[i] -= 0.1f * delta[i];
    delta[i] = 0.f;
  }
}

// ---------------- column sum over nodes -------------------------------------
__global__ void colsum(const float* __restrict__ xn, float* __restrict__ nodesum){
  int col = threadIdx.x % 96;
  int seg = threadIdx.x / 96;
  int stripe = blockIdx.x * 2 + seg;   // 0..399
  float acc = 0.f;
  for (int n = stripe; n < NN; n += 400) acc += xn[(long)n * 96 + col];
  unsafeAtomicAdd(nodesum + col, acc);
}

// ---------------- project to 16 outputs, scale, fp32 store ------------------
__global__ void project(const float* __restrict__ nodesum, const float* __restrict__ siT,
                        float* __restrict__ out){
  int j = threadIdx.x;
  if (j < 16){
    float a = 0.f;
#pragma unroll
    for (int c = 0; c < 96; c++) a += nodesum[c] * siT[j*96 + c];
    out[j] = a * 0.007071067811865475f;   // 1/sqrt(20000)
  }
}

// ---------------- host side -------------------------------------------------
extern "C" void kernel_launch(void* const* d_in, const int* in_sizes, int n_in,
                              void* d_out, int out_size, void* d_ws, size_t ws_size,
                              hipStream_t stream){
  const float* pos  = (const float*)d_in[0];
  const int* atom_z = (const int*)d_in[1];
  const int* esrc   = (const int*)d_in[2];
  const int* edst   = (const int*)d_in[3];

  float* ws      = (float*)d_ws;
  float* basis   = ws;                  // 10*NE = 3,200,000
  float* xn      = ws + 3200000;        // NN*96 = 1,920,000
  float* delta   = ws + 5120000;        // NN*96
  float* nodesum = ws + 7040000;        // 96
  float* WB      = ws + 7040096;        // 87,072 fp32 weights

  float* embedF = WB + 0;        // 160
  float* dl0w1T = WB + 160;      // 256   [32][8]
  float* dl0w2T = WB + 416;      // 1024  [32][32]
  float* dl1w1T = WB + 1440;     // 128   [32][4]
  float* dl1w2T = WB + 1568;     // 1024  [32][32]
  float* f01w1T = WB + 2592;     // 1280  [2][64][10]
  float* f01w2T = WB + 3872;     // 4096  [2][32][64]
  float* wAw1T  = WB + 7968;     // 2560  [2][2][64][10]
  float* wAw2T  = WB + 10528;    // 24576 [2][2][96][64]
  float* wCw1T  = WB + 35104;    // 1280  [2][64][10]
  float* wCw2T  = WB + 36384;    // 24576 [2][192][64]
  float* dlLw1  = WB + 60960;    // 12288 [2][192][32] natural
  float* dlLw2T = WB + 73248;    // 12288 [2][192][32] (T of [32][192])
  float* siT    = WB + 85536;    // 1536  [16][96]

  hipMemsetAsync(delta, 0, (size_t)NN * 96 * 4, stream);
  hipMemsetAsync(nodesum, 0, 96 * 4, stream);

  TTab tb;
  int ti = 0;
  auto add = [&](const void* s, float* dst, int R, int C, int tr){
    tb.e[ti].src = (const float*)s; tb.e[ti].dst = dst;
    tb.e[ti].R = R; tb.e[ti].C = C; tb.e[ti].trans = tr; ti++;
  };
  add(d_in[4],  embedF, 20, 8, 0);
  add(d_in[5],  dl0w1T, 8, 32, 1);
  add(d_in[6],  dl0w2T, 32, 32, 1);
  add(d_in[7],  dl1w1T, 4, 32, 1);
  add(d_in[8],  dl1w2T, 32, 32, 1);
  for (int p = 0; p < 2; p++) add((const float*)d_in[9]  + p*640,  f01w1T + p*640,  10, 64, 1);
  for (int p = 0; p < 2; p++) add((const float*)d_in[10] + p*2048, f01w2T + p*2048, 64, 32, 1);
  for (int q = 0; q < 4; q++) add((const float*)d_in[11] + q*640,  wAw1T + q*640,   10, 64, 1);
  for (int q = 0; q < 4; q++) add((const float*)d_in[12] + q*6144, wAw2T + q*6144,  64, 96, 1);
  for (int i = 0; i < 2; i++) add((const float*)d_in[13] + i*640,   wCw1T + i*640,   10, 64, 1);
  for (int i = 0; i < 2; i++) add((const float*)d_in[14] + i*12288, wCw2T + i*12288, 64, 192, 1);
  for (int i = 0; i < 2; i++) add((const float*)d_in[15] + i*6144,  dlLw1 + i*6144,  192, 32, 0);
  for (int i = 0; i < 2; i++) add((const float*)d_in[16] + i*6144,  dlLw2T + i*6144, 32, 192, 1);
  add(d_in[17], siT, 96, 16, 1);

  convw<<<26, 256, 0, stream>>>(tb);
  node_init<<<(NN + 255)/256, 256, 0, stream>>>(atom_z, embedF, dl0w1T, dl0w2T, xn);
  edge_init<<<(NE + 255)/256, 256, 0, stream>>>(pos, esrc, edst, basis, xn,
                                                dl1w1T, dl1w2T, f01w1T, f01w2T);
  for (int i = 0; i < 2; i++){
    layer_k<<<(NE + 255)/256, 256, 0, stream>>>(basis, esrc, edst, xn, delta,
        wAw1T + (i*2+0)*640, wAw1T + (i*2+1)*640, wCw1T + i*640,
        wAw2T + (i*2+0)*6144, wAw2T + (i*2+1)*6144, wCw2T + i*12288,
        dlLw1 + i*6144, dlLw2T + i*6144);
    node_upd<<<(NN*96 + 255)/256, 256, 0, stream>>>(xn, delta);
  }
  colsum<<<200, 192, 0, stream>>>(xn, nodesum);
  project<<<1, 64, 0, stream>>>(nodesum, siT, (float*)d_out);
}

// Round 3
// 5600.102 us; speedup vs baseline: 1.6653x; 1.6653x over previous
//
#include <hip/hip_runtime.h>
#include <hip/hip_bf16.h>

#define NN 20000
#define NE 320000

// jax.nn.gelu default (approximate=True): 0.5x(1+tanh(t)) == x*sigmoid(2t)
__device__ __forceinline__ float geluf(float x){
  float t = 0.7978845608028654f * x * (1.0f + 0.044715f * x * x);
  return x / (1.0f + __expf(-2.0f * t));
}

// compute bessel basis b[10] from edge geometry via sin recurrence
__device__ __forceinline__ void edge_geom(const float* __restrict__ pos, int s, int d,
                                          float* b, float* vx, float* vy, float* vz,
                                          float* len, float* inv){
  float x = pos[s*3+0] - pos[d*3+0];
  float y = pos[s*3+1] - pos[d*3+1];
  float z = pos[s*3+2] - pos[d*3+2];
  float L = sqrtf(x*x + y*y + z*z + 1e-12f);
  float iv = 1.0f / fmaxf(L, 1e-6f);
  float th = 1.5707963267948966f * L;        // pi*len/2
  float s1 = sinf(th), c1 = cosf(th);
  float scale = iv * 3.1622776601683795f;    // sqrt(2/MAXR)*sqrt(B)/r
  float sp = 0.f, sc = s1, c2 = 2.0f * c1;
  #pragma unroll
  for (int k = 0; k < 10; k++){
    b[k] = sc * scale;
    float sn = c2 * sc - sp;
    sp = sc; sc = sn;
  }
  *vx = x; *vy = y; *vz = z; *len = L; *inv = iv;
}

// ---------------- weight transpose/copy (fp32 -> fp32 in ws) ----------------
struct TEnt { const float* src; float* dst; int R; int C; int trans; };
struct TTab { TEnt e[26]; };

__global__ void convw(TTab t){
  TEnt en = t.e[blockIdx.x];
  int n = en.R * en.C;
  for (int i = threadIdx.x; i < n; i += blockDim.x){
    float v = en.src[i];
    if (en.trans){
      int r = i / en.C, c = i - r * en.C;
      en.dst[c * en.R + r] = v;          // dst[C][R]
    } else {
      en.dst[i] = v;
    }
  }
}

// ---------------- CSR build --------------------------------------------------
__global__ void count_k(const int* __restrict__ esrc, const int* __restrict__ edst,
                        int* __restrict__ cnt){
  int e = blockIdx.x * 256 + threadIdx.x;
  if (e >= NE) return;
  atomicAdd(cnt + edst[e], 1);
  atomicAdd(cnt + esrc[e], 1);
}

__global__ __launch_bounds__(1024) void prefix_k(const int* __restrict__ cnt,
                                                 int* __restrict__ off, int* __restrict__ cur){
  __shared__ int part[1024];
  int t = threadIdx.x;
  int base = t * 20;
  int s = 0;
  for (int i = 0; i < 20; i++){ int idx = base + i; if (idx < NN) s += cnt[idx]; }
  part[t] = s; __syncthreads();
  for (int d = 1; d < 1024; d <<= 1){
    int v = (t >= d) ? part[t - d] : 0;
    __syncthreads();
    part[t] += v;
    __syncthreads();
  }
  int run = (t == 0) ? 0 : part[t - 1];
  for (int i = 0; i < 20; i++){
    int idx = base + i;
    if (idx < NN){ off[idx] = run; cur[idx] = run; run += cnt[idx]; }
  }
  if (t == 0) off[NN] = 2 * NE;
}

__global__ void fill_k(const int* __restrict__ esrc, const int* __restrict__ edst,
                       int* __restrict__ cur, int* __restrict__ inc){
  int e = blockIdx.x * 256 + threadIdx.x;
  if (e >= NE) return;
  int pd = atomicAdd(cur + edst[e], 1);
  inc[pd] = (e << 1);          // role 0: this node is dst
  int ps = atomicAdd(cur + esrc[e], 1);
  inc[ps] = (e << 1) | 1;      // role 1: this node is src
}

// ---------------- node init: xn[:,0:32] = mlp2(embed[z]), zero rest ---------
__global__ __launch_bounds__(256) void node_init(
    const int* __restrict__ az, const float* __restrict__ embedF,
    const float* __restrict__ w1T /*[32][8]*/, const float* __restrict__ w2T /*[32][32]*/,
    float* __restrict__ xn)
{
  int n = blockIdx.x * 256 + threadIdx.x;
  if (n >= NN) return;
  int z = az[n];
  float ee[8];
#pragma unroll
  for (int k = 0; k < 8; k++) ee[k] = embedF[z * 8 + k];
  float hid[32];
#pragma unroll
  for (int l = 0; l < 32; l++){
    float a = 0.f;
#pragma unroll
    for (int k = 0; k < 8; k++) a += ee[k] * w1T[l * 8 + k];
    hid[l] = geluf(a);
  }
  float* row = xn + (long)n * 96;
#pragma unroll
  for (int j = 0; j < 32; j++){
    float a = 0.f;
#pragma unroll
    for (int l = 0; l < 32; l++) a += hid[l] * w2T[j * 32 + l];
    row[j] = a;
  }
#pragma unroll
  for (int j = 32; j < 96; j++) row[j] = 0.f;
}

// ---------------- edge init: per-edge messages (64 floats) ------------------
// msg[e-e0][0:32]  = W0 * xeh        (div payload, sign applied gather-side)
// msg[e-e0][32:64] = 0.5 * W1 * xeh  (ave payload)
__global__ __launch_bounds__(256) void edge_init(
    const float* __restrict__ pos, const int* __restrict__ esrc, const int* __restrict__ edst,
    float* __restrict__ msg, int e0, int e1,
    const float* __restrict__ w1T /*dl1w1T [32][4]*/, const float* __restrict__ w2T /*[32][32]*/,
    const float* __restrict__ f1T /*[2][64][10]*/, const float* __restrict__ f2T /*[2][32][64]*/)
{
  int e = e0 + blockIdx.x * 256 + threadIdx.x;
  if (e >= e1) return;
  int s = esrc[e], d = edst[e];
  float b[10], vx, vy, vz, len, inv;
  edge_geom(pos, s, d, b, &vx, &vy, &vz, &len, &inv);

  float u = len - 2.0f;   // 2*(len/MAXR - 1), MAXR=2
  float cut = 0.5f * (1.0f - cosf(3.14159265358979323f * u));
  cut = (u > 0.0f) ? 0.0f : cut;
  cut = (u < -1.0f) ? 1.0f : cut;
  float xe0 = cut, cc = cut * 1.7320508075688772f * inv;
  float xe1 = cc*vx, xe2 = cc*vy, xe3 = cc*vz;
  float hid[32];
#pragma unroll
  for (int l = 0; l < 32; l++){
    float a = xe0*w1T[l*4+0] + xe1*w1T[l*4+1] + xe2*w1T[l*4+2] + xe3*w1T[l*4+3];
    hid[l] = geluf(a);
  }
  float xeh[32];
#pragma unroll
  for (int j = 0; j < 32; j++){
    float a = 0.f;
#pragma unroll
    for (int l = 0; l < 32; l++) a += hid[l] * w2T[j*32 + l];
    xeh[j] = a;
  }
  float* mrow = msg + (long)(e - e0) * 64;
  float h64[64];
#pragma unroll
  for (int l = 0; l < 64; l++){
    float a = 0.f;
#pragma unroll
    for (int k = 0; k < 10; k++) a += b[k] * f1T[l*10 + k];
    h64[l] = geluf(a);
  }
  for (int jc = 0; jc < 32; jc += 4){
    float4 v;
    float* vp = (float*)&v;
#pragma unroll
    for (int jj = 0; jj < 4; jj++){
      int j = jc + jj;
      float a = 0.f;
#pragma unroll
      for (int l = 0; l < 64; l++) a += h64[l] * f2T[j*64 + l];
      vp[jj] = a * xeh[j];
    }
    *(float4*)(mrow + jc) = v;
  }
#pragma unroll
  for (int l = 0; l < 64; l++){
    float a = 0.f;
#pragma unroll
    for (int k = 0; k < 10; k++) a += b[k] * f1T[640 + l*10 + k];
    h64[l] = geluf(a);
  }
  for (int jc = 0; jc < 32; jc += 4){
    float4 v;
    float* vp = (float*)&v;
#pragma unroll
    for (int jj = 0; jj < 4; jj++){
      int j = jc + jj;
      float a = 0.f;
#pragma unroll
      for (int l = 0; l < 64; l++) a += h64[l] * f2T[2048 + j*64 + l];
      vp[jj] = 0.5f * a * xeh[j];
    }
    *(float4*)(mrow + 32 + jc) = v;
  }
}

// one block (64 threads) per node; cols 32..95 of xn accumulate
__global__ __launch_bounds__(64) void gather_init(
    const int* __restrict__ inc, const int* __restrict__ off,
    const float* __restrict__ msg, float* __restrict__ xn, int e0, int e1)
{
  int n = blockIdx.x;
  int c = threadIdx.x;          // 0..63
  int i0 = off[n], i1 = off[n+1];
  float acc = 0.f;
  for (int ii = i0; ii < i1; ii++){
    int v = inc[ii];
    int e = v >> 1;
    if (e < e0 || e >= e1) continue;
    float m = msg[(long)(e - e0) * 64 + c];
    // first 32 cols: div payload, src side negates; last 32: ave payload
    float sgn = (c < 32 && (v & 1)) ? -1.0f : 1.0f;
    acc += sgn * m;
  }
  xn[(long)n * 96 + 32 + c] += acc;
}

// ---------------- conv layer: per-edge messages (192 floats) ----------------
// msg[e-e0][0:96]   = p = gA+gB   (consumed by dst)
// msg[e-e0][96:192] = q = gB-gA   (consumed by src)
__global__ __launch_bounds__(256) void layer_k(
    const float* __restrict__ pos, const int* __restrict__ esrc,
    const int* __restrict__ edst, const float* __restrict__ xn,
    float* __restrict__ msg, int e0, int e1,
    const float* __restrict__ w1aT, const float* __restrict__ w1bT,
    const float* __restrict__ w1cT, const float* __restrict__ w2aT,
    const float* __restrict__ w2bT, const float* __restrict__ w2cT,
    const float* __restrict__ dw1,  const float* __restrict__ dw2T)
{
  int e = e0 + blockIdx.x * 256 + threadIdx.x;
  if (e >= e1) return;
  int s = esrc[e], d = edst[e];
  float b[10], vx, vy, vz, len, inv;
  edge_geom(pos, s, d, b, &vx, &vy, &vz, &len, &inv);
  const float* xsr = xn + (long)s * 96;
  const float* xdr = xn + (long)d * 96;
  float h[64];
  float hd[32];
#pragma unroll
  for (int l = 0; l < 32; l++) hd[l] = 0.f;

  // ---- pass A: hA = gelu(b@w1a); accumulate grad-part into hd ----
#pragma unroll
  for (int l = 0; l < 64; l++){
    float a = 0.f;
#pragma unroll
    for (int k = 0; k < 10; k++) a += b[k] * w1aT[l*10 + k];
    h[l] = geluf(a);
  }
  for (int jc = 0; jc < 96; jc += 8){
    float4 t0 = *(const float4*)(xsr + jc);
    float4 t1 = *(const float4*)(xsr + jc + 4);
    float4 u0 = *(const float4*)(xdr + jc);
    float4 u1 = *(const float4*)(xdr + jc + 4);
    float xs[8] = {t0.x,t0.y,t0.z,t0.w,t1.x,t1.y,t1.z,t1.w};
    float xd[8] = {u0.x,u0.y,u0.z,u0.w,u1.x,u1.y,u1.z,u1.w};
#pragma unroll
    for (int j = 0; j < 8; j++){
      float a = 0.f;
#pragma unroll
      for (int l = 0; l < 64; l++) a += h[l] * w2aT[(jc+j)*64 + l];
      float g = a * (xd[j] - xs[j]);
#pragma unroll
      for (int l = 0; l < 32; l++) hd[l] += g * dw1[(jc+j)*32 + l];
    }
  }
  // ---- pass B: hB; accumulate ave-part into hd ----
#pragma unroll
  for (int l = 0; l < 64; l++){
    float a = 0.f;
#pragma unroll
    for (int k = 0; k < 10; k++) a += b[k] * w1bT[l*10 + k];
    h[l] = geluf(a);
  }
  for (int jc = 0; jc < 96; jc += 8){
    float4 t0 = *(const float4*)(xsr + jc);
    float4 t1 = *(const float4*)(xsr + jc + 4);
    float4 u0 = *(const float4*)(xdr + jc);
    float4 u1 = *(const float4*)(xdr + jc + 4);
    float xs[8] = {t0.x,t0.y,t0.z,t0.w,t1.x,t1.y,t1.z,t1.w};
    float xd[8] = {u0.x,u0.y,u0.z,u0.w,u1.x,u1.y,u1.z,u1.w};
#pragma unroll
    for (int j = 0; j < 8; j++){
      float a = 0.f;
#pragma unroll
      for (int l = 0; l < 64; l++) a += h[l] * w2bT[(jc+j)*64 + l];
      float g = a * 0.5f * (xd[j] + xs[j]);
#pragma unroll
      for (int l = 0; l < 32; l++) hd[l] += g * dw1[(96+jc+j)*32 + l];
    }
  }
#pragma unroll
  for (int l = 0; l < 32; l++) hd[l] = geluf(hd[l]);
  // ---- hC ----
#pragma unroll
  for (int l = 0; l < 64; l++){
    float a = 0.f;
#pragma unroll
    for (int k = 0; k < 10; k++) a += b[k] * w1cT[l*10 + k];
    h[l] = geluf(a);
  }
  // ---- output: p/q message rows, vectorized stores ----
  float* mrow = msg + (long)(e - e0) * 192;
  for (int jc = 0; jc < 96; jc += 4){
    float4 pv, qv;
    float* pp = (float*)&pv;
    float* qq = (float*)&qv;
#pragma unroll
    for (int jj = 0; jj < 4; jj++){
      int j = jc + jj;
      float d1 = 0.f, d2 = 0.f, c1 = 0.f, c2 = 0.f;
#pragma unroll
      for (int l = 0; l < 32; l++){
        d1 += hd[l] * dw2T[j*32 + l];
        d2 += hd[l] * dw2T[(96+j)*32 + l];
      }
#pragma unroll
      for (int l = 0; l < 64; l++){
        c1 += h[l] * w2cT[j*64 + l];
        c2 += h[l] * w2cT[(96+j)*64 + l];
      }
      float dv = c1 * d1, av = 0.5f * c2 * d2;
      pp[jj] = dv + av;
      qq[jj] = av - dv;
    }
    *(float4*)(mrow + jc) = pv;
    *(float4*)(mrow + 96 + jc) = qv;
  }
}

// one block (128 threads, 96 active) per node; accumulate into delta
__global__ __launch_bounds__(128) void gather_layer(
    const int* __restrict__ inc, const int* __restrict__ off,
    const float* __restrict__ msg, float* __restrict__ delta, int e0, int e1)
{
  int n = blockIdx.x;
  int c = threadIdx.x;
  if (c >= 96) return;
  int i0 = off[n], i1 = off[n+1];
  float acc = 0.f;
  for (int ii = i0; ii < i1; ii++){
    int v = inc[ii];
    int e = v >> 1;
    if (e < e0 || e >= e1) continue;
    acc += msg[(long)(e - e0) * 192 + (v & 1) * 96 + c];
  }
  delta[(long)n * 96 + c] += acc;
}

// ---------------- xn -= h*delta; re-zero delta ------------------------------
__global__ void node_upd(float* __restrict__ xn, float* __restrict__ delta){
  int i = blockIdx.x * 256 + threadIdx.x;
  if (i < NN * 96){
    xn[i] -= 0.1f * delta[i];
    delta[i] = 0.f;
  }
}

// ---------------- column sum over nodes -------------------------------------
__global__ void colsum(const float* __restrict__ xn, float* __restrict__ nodesum){
  int col = threadIdx.x % 96;
  int seg = threadIdx.x / 96;
  int stripe = blockIdx.x * 2 + seg;   // 0..399
  float acc = 0.f;
  for (int n = stripe; n < NN; n += 400) acc += xn[(long)n * 96 + col];
  unsafeAtomicAdd(nodesum + col, acc);
}

// ---------------- project to 16 outputs, scale, fp32 store ------------------
__global__ void project(const float* __restrict__ nodesum, const float* __restrict__ siT,
                        float* __restrict__ out){
  int j = threadIdx.x;
  if (j < 16){
    float a = 0.f;
#pragma unroll
    for (int c = 0; c < 96; c++) a += nodesum[c] * siT[j*96 + c];
    out[j] = a * 0.007071067811865475f;   // 1/sqrt(20000)
  }
}

// ---------------- host side -------------------------------------------------
extern "C" void kernel_launch(void* const* d_in, const int* in_sizes, int n_in,
                              void* d_out, int out_size, void* d_ws, size_t ws_size,
                              hipStream_t stream){
  const float* pos  = (const float*)d_in[0];
  const int* atom_z = (const int*)d_in[1];
  const int* esrc   = (const int*)d_in[2];
  const int* edst   = (const int*)d_in[3];

  float* ws      = (float*)d_ws;
  float* xn      = ws;                  // NN*96 = 1,920,000
  float* delta   = ws + 1920000;        // NN*96
  float* nodesum = ws + 3840000;        // 96
  float* WB      = ws + 3840096;        // 87,072 fp32 weights
  int*   cnt     = (int*)(ws + 3927168);        // 20,000
  int*   cur     = cnt + 20000;                 // 20,000
  int*   off     = cur + 20000;                 // 20,004 (pad)
  int*   inc     = off + 20004;                 // 640,000
  float* msg     = ws + 3927168 + 700004;       // rest: 4,627,172 offset

  long wsFloats  = (long)(ws_size / 4);
  long msgFloats = wsFloats - 4627172L;
  if (msgFloats < 192 * 1024) msgFloats = 192 * 1024;  // last-resort floor
  long CE  = msgFloats / 192; if (CE > NE) CE = NE;    // layer chunk (192 f/edge)
  long CEi = msgFloats / 64;  if (CEi > NE) CEi = NE;  // init chunk  (64 f/edge)

  float* embedF = WB + 0;        // 160
  float* dl0w1T = WB + 160;      // 256   [32][8]
  float* dl0w2T = WB + 416;      // 1024  [32][32]
  float* dl1w1T = WB + 1440;     // 128   [32][4]
  float* dl1w2T = WB + 1568;     // 1024  [32][32]
  float* f01w1T = WB + 2592;     // 1280  [2][64][10]
  float* f01w2T = WB + 3872;     // 4096  [2][32][64]
  float* wAw1T  = WB + 7968;     // 2560  [2][2][64][10]
  float* wAw2T  = WB + 10528;    // 24576 [2][2][96][64]
  float* wCw1T  = WB + 35104;    // 1280  [2][64][10]
  float* wCw2T  = WB + 36384;    // 24576 [2][192][64]
  float* dlLw1  = WB + 60960;    // 12288 [2][192][32] natural
  float* dlLw2T = WB + 73248;    // 12288 [2][192][32] (T of [32][192])
  float* siT    = WB + 85536;    // 1536  [16][96]

  hipMemsetAsync(cnt, 0, 20000 * 4, stream);
  hipMemsetAsync(delta, 0, (size_t)NN * 96 * 4, stream);
  hipMemsetAsync(nodesum, 0, 96 * 4, stream);

  TTab tb;
  int ti = 0;
  auto add = [&](const void* s, float* dst, int R, int C, int tr){
    tb.e[ti].src = (const float*)s; tb.e[ti].dst = dst;
    tb.e[ti].R = R; tb.e[ti].C = C; tb.e[ti].trans = tr; ti++;
  };
  add(d_in[4],  embedF, 20, 8, 0);
  add(d_in[5],  dl0w1T, 8, 32, 1);
  add(d_in[6],  dl0w2T, 32, 32, 1);
  add(d_in[7],  dl1w1T, 4, 32, 1);
  add(d_in[8],  dl1w2T, 32, 32, 1);
  for (int p = 0; p < 2; p++) add((const float*)d_in[9]  + p*640,  f01w1T + p*640,  10, 64, 1);
  for (int p = 0; p < 2; p++) add((const float*)d_in[10] + p*2048, f01w2T + p*2048, 64, 32, 1);
  for (int q = 0; q < 4; q++) add((const float*)d_in[11] + q*640,  wAw1T + q*640,   10, 64, 1);
  for (int q = 0; q < 4; q++) add((const float*)d_in[12] + q*6144, wAw2T + q*6144,  64, 96, 1);
  for (int i = 0; i < 2; i++) add((const float*)d_in[13] + i*640,   wCw1T + i*640,   10, 64, 1);
  for (int i = 0; i < 2; i++) add((const float*)d_in[14] + i*12288, wCw2T + i*12288, 64, 192, 1);
  for (int i = 0; i < 2; i++) add((const float*)d_in[15] + i*6144,  dlLw1 + i*6144,  192, 32, 0);
  for (int i = 0; i < 2; i++) add((const float*)d_in[16] + i*6144,  dlLw2T + i*6144, 32, 192, 1);
  add(d_in[17], siT, 96, 16, 1);

  convw<<<26, 256, 0, stream>>>(tb);
  count_k<<<(NE + 255)/256, 256, 0, stream>>>(esrc, edst, cnt);
  prefix_k<<<1, 1024, 0, stream>>>(cnt, off, cur);
  fill_k<<<(NE + 255)/256, 256, 0, stream>>>(esrc, edst, cur, inc);
  node_init<<<(NN + 255)/256, 256, 0, stream>>>(atom_z, embedF, dl0w1T, dl0w2T, xn);

  for (long e0 = 0; e0 < NE; e0 += CEi){
    long e1 = e0 + CEi; if (e1 > NE) e1 = NE;
    edge_init<<<(int)((e1 - e0 + 255)/256), 256, 0, stream>>>(
        pos, esrc, edst, msg, (int)e0, (int)e1, dl1w1T, dl1w2T, f01w1T, f01w2T);
    gather_init<<<NN, 64, 0, stream>>>(inc, off, msg, xn, (int)e0, (int)e1);
  }

  for (int i = 0; i < 2; i++){
    for (long e0 = 0; e0 < NE; e0 += CE){
      long e1 = e0 + CE; if (e1 > NE) e1 = NE;
      layer_k<<<(int)((e1 - e0 + 255)/256), 256, 0, stream>>>(
          pos, esrc, edst, xn, msg, (int)e0, (int)e1,
          wAw1T + (i*2+0)*640, wAw1T + (i*2+1)*640, wCw1T + i*640,
          wAw2T + (i*2+0)*6144, wAw2T + (i*2+1)*6144, wCw2T + i*12288,
          dlLw1 + i*6144, dlLw2T + i*6144);
      gather_layer<<<NN, 128, 0, stream>>>(inc, off, msg, delta, (int)e0, (int)e1);
    }
    node_upd<<<(NN*96 + 255)/256, 256, 0, stream>>>(xn, delta);
  }
  colsum<<<200, 192, 0, stream>>>(xn, nodesum);
  project<<<1, 64, 0, stream>>>(nodesum, siT, (float*)d_out);
}

// Round 4
// 5113.495 us; speedup vs baseline: 1.8238x; 1.0952x over previous
//
#include <hip/hip_runtime.h>
#include <hip/hip_bf16.h>

#define NN 20000
#define NE 320000

// jax.nn.gelu default (approximate=True): 0.5x(1+tanh(t)) == x*sigmoid(2t)
__device__ __forceinline__ float geluf(float x){
  float t = 0.7978845608028654f * x * (1.0f + 0.044715f * x * x);
  return x / (1.0f + __expf(-2.0f * t));
}

// compute bessel basis b[10] from edge geometry via sin recurrence
__device__ __forceinline__ void edge_geom(const float* __restrict__ pos, int s, int d,
                                          float* b, float* vx, float* vy, float* vz,
                                          float* len, float* inv){
  float x = pos[s*3+0] - pos[d*3+0];
  float y = pos[s*3+1] - pos[d*3+1];
  float z = pos[s*3+2] - pos[d*3+2];
  float L = sqrtf(x*x + y*y + z*z + 1e-12f);
  float iv = 1.0f / fmaxf(L, 1e-6f);
  float th = 1.5707963267948966f * L;        // pi*len/2
  float s1 = sinf(th), c1 = cosf(th);
  float scale = iv * 3.1622776601683795f;    // sqrt(2/MAXR)*sqrt(B)/r
  float sp = 0.f, sc = s1, c2 = 2.0f * c1;
  #pragma unroll
  for (int k = 0; k < 10; k++){
    b[k] = sc * scale;
    float sn = c2 * sc - sp;
    sp = sc; sc = sn;
  }
  *vx = x; *vy = y; *vz = z; *len = L; *inv = iv;
}

// ---------------- weight transpose/copy (fp32 -> fp32 in ws) ----------------
struct TEnt { const float* src; float* dst; int R; int C; int trans; };
struct TTab { TEnt e[26]; };

__global__ void convw(TTab t){
  TEnt en = t.e[blockIdx.x];
  int n = en.R * en.C;
  for (int i = threadIdx.x; i < n; i += blockDim.x){
    float v = en.src[i];
    if (en.trans){
      int r = i / en.C, c = i - r * en.C;
      en.dst[c * en.R + r] = v;          // dst[C][R]
    } else {
      en.dst[i] = v;
    }
  }
}

// ---------------- CSR build --------------------------------------------------
__global__ void count_k(const int* __restrict__ esrc, const int* __restrict__ edst,
                        int* __restrict__ cnt){
  int e = blockIdx.x * 256 + threadIdx.x;
  if (e >= NE) return;
  atomicAdd(cnt + edst[e], 1);
  atomicAdd(cnt + esrc[e], 1);
}

__global__ __launch_bounds__(1024) void prefix_k(const int* __restrict__ cnt,
                                                 int* __restrict__ off, int* __restrict__ cur){
  __shared__ int part[1024];
  int t = threadIdx.x;
  int base = t * 20;
  int s = 0;
  for (int i = 0; i < 20; i++){ int idx = base + i; if (idx < NN) s += cnt[idx]; }
  part[t] = s; __syncthreads();
  for (int d = 1; d < 1024; d <<= 1){
    int v = (t >= d) ? part[t - d] : 0;
    __syncthreads();
    part[t] += v;
    __syncthreads();
  }
  int run = (t == 0) ? 0 : part[t - 1];
  for (int i = 0; i < 20; i++){
    int idx = base + i;
    if (idx < NN){ off[idx] = run; cur[idx] = run; run += cnt[idx]; }
  }
  if (t == 0) off[NN] = 2 * NE;
}

__global__ void fill_k(const int* __restrict__ esrc, const int* __restrict__ edst,
                       int* __restrict__ cur, int* __restrict__ inc){
  int e = blockIdx.x * 256 + threadIdx.x;
  if (e >= NE) return;
  int pd = atomicAdd(cur + edst[e], 1);
  inc[pd] = (e << 1);          // role 0: this node is dst
  int ps = atomicAdd(cur + esrc[e], 1);
  inc[ps] = (e << 1) | 1;      // role 1: this node is src
}

// ---------------- node init: xn[:,0:32] = mlp2(embed[z]), zero rest ---------
__global__ __launch_bounds__(256) void node_init(
    const int* __restrict__ az, const float* __restrict__ embedF,
    const float* __restrict__ w1T /*[32][8]*/, const float* __restrict__ w2T /*[32][32]*/,
    float* __restrict__ xn)
{
  int n = blockIdx.x * 256 + threadIdx.x;
  if (n >= NN) return;
  int z = az[n];
  float ee[8];
#pragma unroll
  for (int k = 0; k < 8; k++) ee[k] = embedF[z * 8 + k];
  float hid[32];
#pragma unroll
  for (int l = 0; l < 32; l++){
    float a = 0.f;
#pragma unroll
    for (int k = 0; k < 8; k++) a += ee[k] * w1T[l * 8 + k];
    hid[l] = geluf(a);
  }
  float* row = xn + (long)n * 96;
#pragma unroll
  for (int j = 0; j < 32; j++){
    float a = 0.f;
#pragma unroll
    for (int l = 0; l < 32; l++) a += hid[l] * w2T[j * 32 + l];
    row[j] = a;
  }
#pragma unroll
  for (int j = 32; j < 96; j++) row[j] = 0.f;
}

// ---------------- edge init: per-edge messages (64 floats) ------------------
// msg[e-e0][0:32]  = W0 * xeh        (div payload, sign applied gather-side)
// msg[e-e0][32:64] = 0.5 * W1 * xeh  (ave payload)
__global__ __launch_bounds__(256) void edge_init(
    const float* __restrict__ pos, const int* __restrict__ esrc, const int* __restrict__ edst,
    float* __restrict__ msg, int e0, int e1,
    const float* __restrict__ w1T /*dl1w1T [32][4]*/, const float* __restrict__ w2T /*[32][32]*/,
    const float* __restrict__ f1T /*[2][64][10]*/, const float* __restrict__ f2T /*[2][32][64]*/)
{
  __shared__ float tile[32 * 256];   // staging for coalesced msg stores
  int t = threadIdx.x;
  int eb = e0 + blockIdx.x * 256;
  int e  = eb + t;
  int nval = e1 - eb; if (nval > 256) nval = 256;
  int ec = (e < e1) ? e : (e1 - 1);

  int s = esrc[ec], d = edst[ec];
  float b[10], vx, vy, vz, len, inv;
  edge_geom(pos, s, d, b, &vx, &vy, &vz, &len, &inv);

  float u = len - 2.0f;   // 2*(len/MAXR - 1), MAXR=2
  float cut = 0.5f * (1.0f - cosf(3.14159265358979323f * u));
  cut = (u > 0.0f) ? 0.0f : cut;
  cut = (u < -1.0f) ? 1.0f : cut;
  float xe0 = cut, cc = cut * 1.7320508075688772f * inv;
  float xe1 = cc*vx, xe2 = cc*vy, xe3 = cc*vz;
  float hid[32];
#pragma unroll
  for (int l = 0; l < 32; l++){
    float a = xe0*w1T[l*4+0] + xe1*w1T[l*4+1] + xe2*w1T[l*4+2] + xe3*w1T[l*4+3];
    hid[l] = geluf(a);
  }
  float xeh[32];
#pragma unroll
  for (int j = 0; j < 32; j++){
    float a = 0.f;
#pragma unroll
    for (int l = 0; l < 32; l++) a += hid[l] * w2T[j*32 + l];
    xeh[j] = a;
  }
  float h64a[64], h64b[64];
#pragma unroll
  for (int l = 0; l < 64; l++){
    float a = 0.f;
#pragma unroll
    for (int k = 0; k < 10; k++) a += b[k] * f1T[l*10 + k];
    h64a[l] = geluf(a);
  }
#pragma unroll
  for (int l = 0; l < 64; l++){
    float a = 0.f;
#pragma unroll
    for (int k = 0; k < 10; k++) a += b[k] * f1T[640 + l*10 + k];
    h64b[l] = geluf(a);
  }
  // msg row = [div(32), ave(32)]; do 2 chunks of (16 div + 16 ave)
  for (int c0 = 0; c0 < 32; c0 += 16){
    __syncthreads();
#pragma unroll
    for (int i = 0; i < 16; i++){
      int j = c0 + i;
      float a = 0.f, v2 = 0.f;
#pragma unroll
      for (int l = 0; l < 64; l++){
        a  += h64a[l] * f2T[j*64 + l];
        v2 += h64b[l] * f2T[2048 + j*64 + l];
      }
      tile[i * 256 + t]        = a * xeh[j];
      tile[(16 + i) * 256 + t] = 0.5f * v2 * xeh[j];
    }
    __syncthreads();
#pragma unroll
    for (int it = 0; it < 4; it++){
      int flat = it * 256 + t;        // float4 id, 1024 total
      int er = flat >> 2, c4 = flat & 3;
      if (er < nval){
        float4 v, w;
        v.x = tile[(c4*4+0)*256 + er];
        v.y = tile[(c4*4+1)*256 + er];
        v.z = tile[(c4*4+2)*256 + er];
        v.w = tile[(c4*4+3)*256 + er];
        w.x = tile[(16+c4*4+0)*256 + er];
        w.y = tile[(16+c4*4+1)*256 + er];
        w.z = tile[(16+c4*4+2)*256 + er];
        w.w = tile[(16+c4*4+3)*256 + er];
        long mb = (long)(eb - e0 + er) * 64;
        *(float4*)(msg + mb + c0 + c4*4)      = v;
        *(float4*)(msg + mb + 32 + c0 + c4*4) = w;
      }
    }
  }
}

// one block (64 threads) per node; cols 32..95 of xn accumulate
__global__ __launch_bounds__(64) void gather_init(
    const int* __restrict__ inc, const int* __restrict__ off,
    const float* __restrict__ msg, float* __restrict__ xn, int e0, int e1)
{
  int n = blockIdx.x;
  int c = threadIdx.x;          // 0..63
  int i0 = off[n], i1 = off[n+1];
  float acc = 0.f;
  for (int ii = i0; ii < i1; ii++){
    int v = inc[ii];
    int e = v >> 1;
    if (e < e0 || e >= e1) continue;
    float m = msg[(long)(e - e0) * 64 + c];
    // first 32 cols: div payload, src side negates; last 32: ave payload
    float sgn = (c < 32 && (v & 1)) ? -1.0f : 1.0f;
    acc += sgn * m;
  }
  xn[(long)n * 96 + 32 + c] += acc;
}

// ---------------- conv layer: per-edge messages (192 floats) ----------------
// msg[e-e0][0:96]   = p = gA+gB   (consumed by dst)
// msg[e-e0][96:192] = q = gB-gA   (consumed by src)
__global__ __launch_bounds__(256) void layer_k(
    const float* __restrict__ pos, const int* __restrict__ esrc,
    const int* __restrict__ edst, const float* __restrict__ xn,
    float* __restrict__ msg, int e0, int e1,
    const float* __restrict__ w1aT, const float* __restrict__ w1bT,
    const float* __restrict__ w1cT, const float* __restrict__ w2aT,
    const float* __restrict__ w2bT, const float* __restrict__ w2cT,
    const float* __restrict__ dw1,  const float* __restrict__ dw2T)
{
  __shared__ float tile[32 * 256];   // staging for coalesced msg stores
  int t = threadIdx.x;
  int eb = e0 + blockIdx.x * 256;
  int e  = eb + t;
  int nval = e1 - eb; if (nval > 256) nval = 256;
  int ec = (e < e1) ? e : (e1 - 1);

  int s = esrc[ec], d = edst[ec];
  float b[10], vx, vy, vz, len, inv;
  edge_geom(pos, s, d, b, &vx, &vy, &vz, &len, &inv);
  const float* xsr = xn + (long)s * 96;
  const float* xdr = xn + (long)d * 96;
  float h[64];
  float hd[32];
#pragma unroll
  for (int l = 0; l < 32; l++) hd[l] = 0.f;

  // ---- pass A: hA = gelu(b@w1a); accumulate grad-part into hd ----
#pragma unroll
  for (int l = 0; l < 64; l++){
    float a = 0.f;
#pragma unroll
    for (int k = 0; k < 10; k++) a += b[k] * w1aT[l*10 + k];
    h[l] = geluf(a);
  }
  for (int jc = 0; jc < 96; jc += 8){
    float4 t0 = *(const float4*)(xsr + jc);
    float4 t1 = *(const float4*)(xsr + jc + 4);
    float4 u0 = *(const float4*)(xdr + jc);
    float4 u1 = *(const float4*)(xdr + jc + 4);
    float xs[8] = {t0.x,t0.y,t0.z,t0.w,t1.x,t1.y,t1.z,t1.w};
    float xd[8] = {u0.x,u0.y,u0.z,u0.w,u1.x,u1.y,u1.z,u1.w};
#pragma unroll
    for (int j = 0; j < 8; j++){
      float a = 0.f;
#pragma unroll
      for (int l = 0; l < 64; l++) a += h[l] * w2aT[(jc+j)*64 + l];
      float g = a * (xd[j] - xs[j]);
#pragma unroll
      for (int l = 0; l < 32; l++) hd[l] += g * dw1[(jc+j)*32 + l];
    }
  }
  // ---- pass B: hB; accumulate ave-part into hd ----
#pragma unroll
  for (int l = 0; l < 64; l++){
    float a = 0.f;
#pragma unroll
    for (int k = 0; k < 10; k++) a += b[k] * w1bT[l*10 + k];
    h[l] = geluf(a);
  }
  for (int jc = 0; jc < 96; jc += 8){
    float4 t0 = *(const float4*)(xsr + jc);
    float4 t1 = *(const float4*)(xsr + jc + 4);
    float4 u0 = *(const float4*)(xdr + jc);
    float4 u1 = *(const float4*)(xdr + jc + 4);
    float xs[8] = {t0.x,t0.y,t0.z,t0.w,t1.x,t1.y,t1.z,t1.w};
    float xd[8] = {u0.x,u0.y,u0.z,u0.w,u1.x,u1.y,u1.z,u1.w};
#pragma unroll
    for (int j = 0; j < 8; j++){
      float a = 0.f;
#pragma unroll
      for (int l = 0; l < 64; l++) a += h[l] * w2bT[(jc+j)*64 + l];
      float g = a * 0.5f * (xd[j] + xs[j]);
#pragma unroll
      for (int l = 0; l < 32; l++) hd[l] += g * dw1[(96+jc+j)*32 + l];
    }
  }
#pragma unroll
  for (int l = 0; l < 32; l++) hd[l] = geluf(hd[l]);
  // ---- hC ----
#pragma unroll
  for (int l = 0; l < 64; l++){
    float a = 0.f;
#pragma unroll
    for (int k = 0; k < 10; k++) a += b[k] * w1cT[l*10 + k];
    h[l] = geluf(a);
  }
  // ---- output: p/q in 16-col chunks, LDS transpose, coalesced stores ----
  for (int c0 = 0; c0 < 96; c0 += 16){
    float pj[16], qj[16];
#pragma unroll
    for (int i = 0; i < 16; i++){
      int j = c0 + i;
      float d1 = 0.f, d2 = 0.f, c1 = 0.f, c2 = 0.f;
#pragma unroll
      for (int l = 0; l < 32; l++){
        d1 += hd[l] * dw2T[j*32 + l];
        d2 += hd[l] * dw2T[(96+j)*32 + l];
      }
#pragma unroll
      for (int l = 0; l < 64; l++){
        c1 += h[l] * w2cT[j*64 + l];
        c2 += h[l] * w2cT[(96+j)*64 + l];
      }
      float dv = c1 * d1, av = 0.5f * c2 * d2;
      pj[i] = dv + av;
      qj[i] = av - dv;
    }
    __syncthreads();   // previous chunk's tile fully consumed
#pragma unroll
    for (int i = 0; i < 16; i++){
      tile[i * 256 + t]        = pj[i];
      tile[(16 + i) * 256 + t] = qj[i];
    }
    __syncthreads();
#pragma unroll
    for (int it = 0; it < 4; it++){
      int flat = it * 256 + t;        // float4 id, 1024 total
      int er = flat >> 2, c4 = flat & 3;
      if (er < nval){
        float4 v, w;
        v.x = tile[(c4*4+0)*256 + er];
        v.y = tile[(c4*4+1)*256 + er];
        v.z = tile[(c4*4+2)*256 + er];
        v.w = tile[(c4*4+3)*256 + er];
        w.x = tile[(16+c4*4+0)*256 + er];
        w.y = tile[(16+c4*4+1)*256 + er];
        w.z = tile[(16+c4*4+2)*256 + er];
        w.w = tile[(16+c4*4+3)*256 + er];
        long mb = (long)(eb - e0 + er) * 192;
        *(float4*)(msg + mb + c0 + c4*4)      = v;
        *(float4*)(msg + mb + 96 + c0 + c4*4) = w;
      }
    }
  }
}

// one block (128 threads, 96 active) per node; accumulate into delta
__global__ __launch_bounds__(128) void gather_layer(
    const int* __restrict__ inc, const int* __restrict__ off,
    const float* __restrict__ msg, float* __restrict__ delta, int e0, int e1)
{
  int n = blockIdx.x;
  int c = threadIdx.x;
  if (c >= 96) return;
  int i0 = off[n], i1 = off[n+1];
  float acc = 0.f;
  for (int ii = i0; ii < i1; ii++){
    int v = inc[ii];
    int e = v >> 1;
    if (e < e0 || e >= e1) continue;
    acc += msg[(long)(e - e0) * 192 + (v & 1) * 96 + c];
  }
  delta[(long)n * 96 + c] += acc;
}

// ---------------- xn -= h*delta; re-zero delta ------------------------------
__global__ void node_upd(float* __restrict__ xn, float* __restrict__ delta){
  int i = blockIdx.x * 256 + threadIdx.x;
  if (i < NN * 96){
    xn[i] -= 0.1f * delta[i];
    delta[i] = 0.f;
  }
}

// ---------------- column sum over nodes -------------------------------------
__global__ void colsum(const float* __restrict__ xn, float* __restrict__ nodesum){
  int col = threadIdx.x % 96;
  int seg = threadIdx.x / 96;
  int stripe = blockIdx.x * 2 + seg;   // 0..399
  float acc = 0.f;
  for (int n = stripe; n < NN; n += 400) acc += xn[(long)n * 96 + col];
  unsafeAtomicAdd(nodesum + col, acc);
}

// ---------------- project to 16 outputs, scale, fp32 store ------------------
__global__ void project(const float* __restrict__ nodesum, const float* __restrict__ siT,
                        float* __restrict__ out){
  int j = threadIdx.x;
  if (j < 16){
    float a = 0.f;
#pragma unroll
    for (int c = 0; c < 96; c++) a += nodesum[c] * siT[j*96 + c];
    out[j] = a * 0.007071067811865475f;   // 1/sqrt(20000)
  }
}

// ---------------- host side -------------------------------------------------
extern "C" void kernel_launch(void* const* d_in, const int* in_sizes, int n_in,
                              void* d_out, int out_size, void* d_ws, size_t ws_size,
                              hipStream_t stream){
  const float* pos  = (const float*)d_in[0];
  const int* atom_z = (const int*)d_in[1];
  const int* esrc   = (const int*)d_in[2];
  const int* edst   = (const int*)d_in[3];

  float* ws      = (float*)d_ws;
  float* xn      = ws;                  // NN*96 = 1,920,000
  float* delta   = ws + 1920000;        // NN*96
  float* nodesum = ws + 3840000;        // 96
  float* WB      = ws + 3840096;        // 87,072 fp32 weights
  int*   cnt     = (int*)(ws + 3927168);        // 20,000
  int*   cur     = cnt + 20000;                 // 20,000
  int*   off     = cur + 20000;                 // 20,004 (pad)
  int*   inc     = off + 20004;                 // 640,000
  float* msg     = ws + 3927168 + 700004;       // rest: 4,627,172 offset

  long wsFloats  = (long)(ws_size / 4);
  long msgFloats = wsFloats - 4627172L;
  if (msgFloats < 192 * 1024) msgFloats = 192 * 1024;  // last-resort floor
  long CE  = msgFloats / 192; if (CE > NE) CE = NE;    // layer chunk (192 f/edge)
  long CEi = msgFloats / 64;  if (CEi > NE) CEi = NE;  // init chunk  (64 f/edge)

  float* embedF = WB + 0;        // 160
  float* dl0w1T = WB + 160;      // 256   [32][8]
  float* dl0w2T = WB + 416;      // 1024  [32][32]
  float* dl1w1T = WB + 1440;     // 128   [32][4]
  float* dl1w2T = WB + 1568;     // 1024  [32][32]
  float* f01w1T = WB + 2592;     // 1280  [2][64][10]
  float* f01w2T = WB + 3872;     // 4096  [2][32][64]
  float* wAw1T  = WB + 7968;     // 2560  [2][2][64][10]
  float* wAw2T  = WB + 10528;    // 24576 [2][2][96][64]
  float* wCw1T  = WB + 35104;    // 1280  [2][64][10]
  float* wCw2T  = WB + 36384;    // 24576 [2][192][64]
  float* dlLw1  = WB + 60960;    // 12288 [2][192][32] natural
  float* dlLw2T = WB + 73248;    // 12288 [2][192][32] (T of [32][192])
  float* siT    = WB + 85536;    // 1536  [16][96]

  hipMemsetAsync(cnt, 0, 20000 * 4, stream);
  hipMemsetAsync(delta, 0, (size_t)NN * 96 * 4, stream);
  hipMemsetAsync(nodesum, 0, 96 * 4, stream);

  TTab tb;
  int ti = 0;
  auto add = [&](const void* s, float* dst, int R, int C, int tr){
    tb.e[ti].src = (const float*)s; tb.e[ti].dst = dst;
    tb.e[ti].R = R; tb.e[ti].C = C; tb.e[ti].trans = tr; ti++;
  };
  add(d_in[4],  embedF, 20, 8, 0);
  add(d_in[5],  dl0w1T, 8, 32, 1);
  add(d_in[6],  dl0w2T, 32, 32, 1);
  add(d_in[7],  dl1w1T, 4, 32, 1);
  add(d_in[8],  dl1w2T, 32, 32, 1);
  for (int p = 0; p < 2; p++) add((const float*)d_in[9]  + p*640,  f01w1T + p*640,  10, 64, 1);
  for (int p = 0; p < 2; p++) add((const float*)d_in[10] + p*2048, f01w2T + p*2048, 64, 32, 1);
  for (int q = 0; q < 4; q++) add((const float*)d_in[11] + q*640,  wAw1T + q*640,   10, 64, 1);
  for (int q = 0; q < 4; q++) add((const float*)d_in[12] + q*6144, wAw2T + q*6144,  64, 96, 1);
  for (int i = 0; i < 2; i++) add((const float*)d_in[13] + i*640,   wCw1T + i*640,   10, 64, 1);
  for (int i = 0; i < 2; i++) add((const float*)d_in[14] + i*12288, wCw2T + i*12288, 64, 192, 1);
  for (int i = 0; i < 2; i++) add((const float*)d_in[15] + i*6144,  dlLw1 + i*6144,  192, 32, 0);
  for (int i = 0; i < 2; i++) add((const float*)d_in[16] + i*6144,  dlLw2T + i*6144, 32, 192, 1);
  add(d_in[17], siT, 96, 16, 1);

  convw<<<26, 256, 0, stream>>>(tb);
  count_k<<<(NE + 255)/256, 256, 0, stream>>>(esrc, edst, cnt);
  prefix_k<<<1, 1024, 0, stream>>>(cnt, off, cur);
  fill_k<<<(NE + 255)/256, 256, 0, stream>>>(esrc, edst, cur, inc);
  node_init<<<(NN + 255)/256, 256, 0, stream>>>(atom_z, embedF, dl0w1T, dl0w2T, xn);

  for (long e0 = 0; e0 < NE; e0 += CEi){
    long e1 = e0 + CEi; if (e1 > NE) e1 = NE;
    edge_init<<<(int)((e1 - e0 + 255)/256), 256, 0, stream>>>(
        pos, esrc, edst, msg, (int)e0, (int)e1, dl1w1T, dl1w2T, f01w1T, f01w2T);
    gather_init<<<NN, 64, 0, stream>>>(inc, off, msg, xn, (int)e0, (int)e1);
  }

  for (int i = 0; i < 2; i++){
    for (long e0 = 0; e0 < NE; e0 += CE){
      long e1 = e0 + CE; if (e1 > NE) e1 = NE;
      layer_k<<<(int)((e1 - e0 + 255)/256), 256, 0, stream>>>(
          pos, esrc, edst, xn, msg, (int)e0, (int)e1,
          wAw1T + (i*2+0)*640, wAw1T + (i*2+1)*640, wCw1T + i*640,
          wAw2T + (i*2+0)*6144, wAw2T + (i*2+1)*6144, wCw2T + i*12288,
          dlLw1 + i*6144, dlLw2T + i*6144);
      gather_layer<<<NN, 128, 0, stream>>>(inc, off, msg, delta, (int)e0, (int)e1);
    }
    node_upd<<<(NN*96 + 255)/256, 256, 0, stream>>>(xn, delta);
  }
  colsum<<<200, 192, 0, stream>>>(xn, nodesum);
  project<<<1, 64, 0, stream>>>(nodesum, siT, (float*)d_out);
}

// Round 5
// 1685.901 us; speedup vs baseline: 5.5317x; 3.0331x over previous
//
#include <hip/hip_runtime.h>
#include <hip/hip_bf16.h>

#define NN 20000
#define NE 320000

typedef _Float16 h2f __attribute__((ext_vector_type(2)));

__device__ __forceinline__ h2f u2h(unsigned int u){
  union { unsigned int u; h2f h; } v; v.u = u; return v.h;
}
__device__ __forceinline__ float dot2(unsigned int w, h2f x, float acc){
#if __has_builtin(__builtin_amdgcn_fdot2)
  return __builtin_amdgcn_fdot2(u2h(w), x, acc, false);
#else
  h2f c = u2h(w);
  return acc + (float)(c.x) * (float)(x.x) + (float)(c.y) * (float)(x.y);
#endif
}

// jax.nn.gelu default (approximate=True): 0.5x(1+tanh(t)) == x*sigmoid(2t)
__device__ __forceinline__ float geluf(float x){
  float t = 0.7978845608028654f * x * (1.0f + 0.044715f * x * x);
  return x / (1.0f + __expf(-2.0f * t));
}

// compute bessel basis b[10] from edge geometry via sin recurrence
__device__ __forceinline__ void edge_geom(const float* __restrict__ pos, int s, int d,
                                          float* b, float* vx, float* vy, float* vz,
                                          float* len, float* inv){
  float x = pos[s*3+0] - pos[d*3+0];
  float y = pos[s*3+1] - pos[d*3+1];
  float z = pos[s*3+2] - pos[d*3+2];
  float L = sqrtf(x*x + y*y + z*z + 1e-12f);
  float iv = 1.0f / fmaxf(L, 1e-6f);
  float th = 1.5707963267948966f * L;        // pi*len/2
  float s1 = sinf(th), c1 = cosf(th);
  float scale = iv * 3.1622776601683795f;    // sqrt(2/MAXR)*sqrt(B)/r
  float sp = 0.f, sc = s1, c2 = 2.0f * c1;
  #pragma unroll
  for (int k = 0; k < 10; k++){
    b[k] = sc * scale;
    float sn = c2 * sc - sp;
    sp = sc; sc = sn;
  }
  *vx = x; *vy = y; *vz = z; *len = L; *inv = iv;
}

// ---------------- weight transpose/copy (fp32 -> fp32 in ws) ----------------
struct TEnt { const float* src; float* dst; int R; int C; int trans; };
struct TTab { TEnt e[16]; };

__global__ void convw(TTab t){
  TEnt en = t.e[blockIdx.x];
  int n = en.R * en.C;
  for (int i = threadIdx.x; i < n; i += blockDim.x){
    float v = en.src[i];
    if (en.trans){
      int r = i / en.C, c = i - r * en.C;
      en.dst[c * en.R + r] = v;          // dst[C][R]
    } else {
      en.dst[i] = v;
    }
  }
}

// ---------------- pack fp32 [R][C] -> f16-pair uints [C][R/2] ---------------
// dst[c*(R/2)+rp] = pack(src[2rp][c], src[2rp+1][c])  (pairs over R)
struct PEnt { const float* src; unsigned int* dst; int R; int C; };
struct PTab { PEnt e[10]; };

__global__ void packw(PTab t){
  PEnt en = t.e[blockIdx.x];
  int half = en.R >> 1;
  int n = en.C * half;
  for (int i = threadIdx.x; i < n; i += blockDim.x){
    int c = i / half, rp = i - c * half;
    float a = en.src[(2*rp)     * en.C + c];
    float b = en.src[(2*rp + 1) * en.C + c];
    h2f h; h.x = (_Float16)a; h.y = (_Float16)b;
    union { h2f h; unsigned int u; } v; v.h = h;
    en.dst[i] = v.u;
  }
}

// ---------------- CSR build --------------------------------------------------
__global__ void count_k(const int* __restrict__ esrc, const int* __restrict__ edst,
                        int* __restrict__ cnt){
  int e = blockIdx.x * 256 + threadIdx.x;
  if (e >= NE) return;
  atomicAdd(cnt + edst[e], 1);
  atomicAdd(cnt + esrc[e], 1);
}

__global__ __launch_bounds__(1024) void prefix_k(const int* __restrict__ cnt,
                                                 int* __restrict__ off, int* __restrict__ cur){
  __shared__ int part[1024];
  int t = threadIdx.x;
  int base = t * 20;
  int s = 0;
  for (int i = 0; i < 20; i++){ int idx = base + i; if (idx < NN) s += cnt[idx]; }
  part[t] = s; __syncthreads();
  for (int d = 1; d < 1024; d <<= 1){
    int v = (t >= d) ? part[t - d] : 0;
    __syncthreads();
    part[t] += v;
    __syncthreads();
  }
  int run = (t == 0) ? 0 : part[t - 1];
  for (int i = 0; i < 20; i++){
    int idx = base + i;
    if (idx < NN){ off[idx] = run; cur[idx] = run; run += cnt[idx]; }
  }
  if (t == 0) off[NN] = 2 * NE;
}

__global__ void fill_k(const int* __restrict__ esrc, const int* __restrict__ edst,
                       int* __restrict__ cur, int* __restrict__ inc){
  int e = blockIdx.x * 256 + threadIdx.x;
  if (e >= NE) return;
  int pd = atomicAdd(cur + edst[e], 1);
  inc[pd] = (e << 1);          // role 0: this node is dst
  int ps = atomicAdd(cur + esrc[e], 1);
  inc[ps] = (e << 1) | 1;      // role 1: this node is src
}

// ---------------- node init: xn[:,0:32] = mlp2(embed[z]), zero rest ---------
__global__ __launch_bounds__(256) void node_init(
    const int* __restrict__ az, const float* __restrict__ embedF,
    const float* __restrict__ w1T /*[32][8]*/, const float* __restrict__ w2T /*[32][32]*/,
    float* __restrict__ xn)
{
  int n = blockIdx.x * 256 + threadIdx.x;
  if (n >= NN) return;
  int z = az[n];
  float ee[8];
#pragma unroll
  for (int k = 0; k < 8; k++) ee[k] = embedF[z * 8 + k];
  float hid[32];
#pragma unroll
  for (int l = 0; l < 32; l++){
    float a = 0.f;
#pragma unroll
    for (int k = 0; k < 8; k++) a += ee[k] * w1T[l * 8 + k];
    hid[l] = geluf(a);
  }
  float* row = xn + (long)n * 96;
#pragma unroll
  for (int j = 0; j < 32; j++){
    float a = 0.f;
#pragma unroll
    for (int l = 0; l < 32; l++) a += hid[l] * w2T[j * 32 + l];
    row[j] = a;
  }
#pragma unroll
  for (int j = 32; j < 96; j++) row[j] = 0.f;
}

// ---------------- edge init: per-edge messages (64 floats) ------------------
// msg[e-e0][0:32]  = W0 * xeh        (div payload, sign applied gather-side)
// msg[e-e0][32:64] = 0.5 * W1 * xeh  (ave payload)
__global__ __launch_bounds__(256) void edge_init(
    const float* __restrict__ pos, const int* __restrict__ esrc, const int* __restrict__ edst,
    float* __restrict__ msg, int e0, int e1,
    const float* __restrict__ w1T /*dl1w1T [32][4]*/, const float* __restrict__ w2T /*[32][32]*/,
    const float* __restrict__ f1T /*[2][64][10]*/, const float* __restrict__ f2T /*[2][32][64]*/)
{
  int e = e0 + blockIdx.x * 256 + threadIdx.x;
  if (e >= e1) return;
  int s = esrc[e], d = edst[e];
  float b[10], vx, vy, vz, len, inv;
  edge_geom(pos, s, d, b, &vx, &vy, &vz, &len, &inv);

  float u = len - 2.0f;   // 2*(len/MAXR - 1), MAXR=2
  float cut = 0.5f * (1.0f - cosf(3.14159265358979323f * u));
  cut = (u > 0.0f) ? 0.0f : cut;
  cut = (u < -1.0f) ? 1.0f : cut;
  float xe0 = cut, cc = cut * 1.7320508075688772f * inv;
  float xe1 = cc*vx, xe2 = cc*vy, xe3 = cc*vz;
  float hid[32];
#pragma unroll
  for (int l = 0; l < 32; l++){
    float a = xe0*w1T[l*4+0] + xe1*w1T[l*4+1] + xe2*w1T[l*4+2] + xe3*w1T[l*4+3];
    hid[l] = geluf(a);
  }
  float xeh[32];
#pragma unroll
  for (int j = 0; j < 32; j++){
    float a = 0.f;
#pragma unroll
    for (int l = 0; l < 32; l++) a += hid[l] * w2T[j*32 + l];
    xeh[j] = a;
  }
  float* mrow = msg + (long)(e - e0) * 64;
  float h64[64];
#pragma unroll
  for (int l = 0; l < 64; l++){
    float a = 0.f;
#pragma unroll
    for (int k = 0; k < 10; k++) a += b[k] * f1T[l*10 + k];
    h64[l] = geluf(a);
  }
  for (int jc = 0; jc < 32; jc += 4){
    float4 v;
    float* vp = (float*)&v;
#pragma unroll
    for (int jj = 0; jj < 4; jj++){
      int j = jc + jj;
      float a = 0.f;
#pragma unroll
      for (int l = 0; l < 64; l++) a += h64[l] * f2T[j*64 + l];
      vp[jj] = a * xeh[j];
    }
    *(float4*)(mrow + jc) = v;
  }
#pragma unroll
  for (int l = 0; l < 64; l++){
    float a = 0.f;
#pragma unroll
    for (int k = 0; k < 10; k++) a += b[k] * f1T[640 + l*10 + k];
    h64[l] = geluf(a);
  }
  for (int jc = 0; jc < 32; jc += 4){
    float4 v;
    float* vp = (float*)&v;
#pragma unroll
    for (int jj = 0; jj < 4; jj++){
      int j = jc + jj;
      float a = 0.f;
#pragma unroll
      for (int l = 0; l < 64; l++) a += h64[l] * f2T[2048 + j*64 + l];
      vp[jj] = 0.5f * a * xeh[j];
    }
    *(float4*)(mrow + 32 + jc) = v;
  }
}

// one block (64 threads) per node; cols 32..95 of xn accumulate
__global__ __launch_bounds__(64) void gather_init(
    const int* __restrict__ inc, const int* __restrict__ off,
    const float* __restrict__ msg, float* __restrict__ xn, int e0, int e1)
{
  int n = blockIdx.x;
  int c = threadIdx.x;          // 0..63
  int i0 = off[n], i1 = off[n+1];
  float acc = 0.f;
  for (int ii = i0; ii < i1; ii++){
    int v = inc[ii];
    int e = v >> 1;
    if (e < e0 || e >= e1) continue;
    float m = msg[(long)(e - e0) * 64 + c];
    // first 32 cols: div payload, src side negates; last 32: ave payload
    float sgn = (c < 32 && (v & 1)) ? -1.0f : 1.0f;
    acc += sgn * m;
  }
  xn[(long)n * 96 + 32 + c] += acc;
}

// ---------------- conv layer: f16-dot2 with LDS-staged weights --------------
// msg[e-e0][0:96]   = p = gA+gB   (consumed by dst)
// msg[e-e0][96:192] = q = gB-gA   (consumed by src)
// pk layout (uints): w2a[96][32] @0, w2b[96][32] @3072, dw1T[32][96] @6144,
//                    w2c[192][32] @9216, dw2[192][16] @15360   (total 18432)
__global__ __launch_bounds__(512, 4) void layer_k(
    const float* __restrict__ pos, const int* __restrict__ esrc,
    const int* __restrict__ edst, const float* __restrict__ xn,
    float* __restrict__ msg, int e0, int e1,
    const float* __restrict__ w1aT, const float* __restrict__ w1bT,
    const float* __restrict__ w1cT, const unsigned int* __restrict__ pk)
{
  __shared__ uint4 lw4[4608];          // 72 KB packed-f16 weights
  unsigned int* lw = (unsigned int*)lw4;
  int t = threadIdx.x;
  {
    const uint4* s4 = (const uint4*)pk;
    for (int i = t; i < 4608; i += 512) lw4[i] = s4[i];
  }
  __syncthreads();
  int e = e0 + blockIdx.x * 512 + t;
  if (e >= e1) return;

  const unsigned int* w2a  = lw;
  const unsigned int* w2b  = lw + 3072;
  const unsigned int* dw1T = lw + 6144;
  const unsigned int* w2c  = lw + 9216;
  const unsigned int* dw2  = lw + 15360;

  int s = esrc[e], d = edst[e];
  float b10[10], vx, vy, vz, len, inv;
  edge_geom(pos, s, d, b10, &vx, &vy, &vz, &len, &inv);
  const float* xsr = xn + (long)s * 96;
  const float* xdr = xn + (long)d * 96;

  float hd[32];
#pragma unroll
  for (int l = 0; l < 32; l++) hd[l] = 0.f;

  // ---- passes A (grad) and B (ave): hd += dlL_w1^T @ (W*(x combo)) --------
#pragma unroll 1
  for (int pp = 0; pp < 2; pp++){
    const float* w1 = pp ? w1bT : w1aT;
    const unsigned int* w2 = pp ? w2b : w2a;
    int jbase = pp ? 48 : 0;   // dw1T pair-column offset (j in [96,192))

    h2f hp[32];
#pragma unroll
    for (int lp = 0; lp < 32; lp++){
      float a0 = 0.f, a1 = 0.f;
#pragma unroll
      for (int k = 0; k < 10; k++){
        a0 += b10[k] * w1[(2*lp)  *10 + k];
        a1 += b10[k] * w1[(2*lp+1)*10 + k];
      }
      h2f r; r.x = (_Float16)geluf(a0); r.y = (_Float16)geluf(a1);
      hp[lp] = r;
    }

    for (int jc = 0; jc < 96; jc += 8){
      float4 t0 = *(const float4*)(xsr + jc);
      float4 t1 = *(const float4*)(xsr + jc + 4);
      float4 u0 = *(const float4*)(xdr + jc);
      float4 u1 = *(const float4*)(xdr + jc + 4);
      float xs[8] = {t0.x,t0.y,t0.z,t0.w,t1.x,t1.y,t1.z,t1.w};
      float xd[8] = {u0.x,u0.y,u0.z,u0.w,u1.x,u1.y,u1.z,u1.w};

      h2f gp[4];
#pragma unroll
      for (int p = 0; p < 4; p++){
        float gg[2];
#pragma unroll
        for (int w = 0; w < 2; w++){
          int j = jc + 2*p + w;
          const uint4* wr = (const uint4*)(w2 + j*32);
          float a = 0.f;
#pragma unroll
          for (int q = 0; q < 8; q++){
            uint4 ww = wr[q];
            a = dot2(ww.x, hp[q*4+0], a);
            a = dot2(ww.y, hp[q*4+1], a);
            a = dot2(ww.z, hp[q*4+2], a);
            a = dot2(ww.w, hp[q*4+3], a);
          }
          float xv = pp ? 0.5f*(xd[2*p+w] + xs[2*p+w]) : (xd[2*p+w] - xs[2*p+w]);
          gg[w] = a * xv * 0.125f;     // 1/8 scale for f16 range
        }
        h2f r; r.x = (_Float16)gg[0]; r.y = (_Float16)gg[1];
        gp[p] = r;
      }
      int jp0 = jbase + (jc >> 1);
#pragma unroll
      for (int l = 0; l < 32; l++){
        uint4 ww = *(const uint4*)(dw1T + l*96 + jp0);
        float acc = hd[l];
        acc = dot2(ww.x, gp[0], acc);
        acc = dot2(ww.y, gp[1], acc);
        acc = dot2(ww.z, gp[2], acc);
        acc = dot2(ww.w, gp[3], acc);
        hd[l] = acc;
      }
    }
  }

  // ---- hd gelu (undo 1/8), pack at 1/8 for output dots ----
  h2f hdp[16];
#pragma unroll
  for (int lp = 0; lp < 16; lp++){
    h2f r;
    r.x = (_Float16)(geluf(8.f*hd[2*lp])   * 0.125f);
    r.y = (_Float16)(geluf(8.f*hd[2*lp+1]) * 0.125f);
    hdp[lp] = r;
  }
  // ---- hC ----
  h2f hcp[32];
#pragma unroll
  for (int lp = 0; lp < 32; lp++){
    float a0 = 0.f, a1 = 0.f;
#pragma unroll
    for (int k = 0; k < 10; k++){
      a0 += b10[k] * w1cT[(2*lp)  *10 + k];
      a1 += b10[k] * w1cT[(2*lp+1)*10 + k];
    }
    h2f r; r.x = (_Float16)geluf(a0); r.y = (_Float16)geluf(a1);
    hcp[lp] = r;
  }

  // ---- output: dxe = hd@dlL_w2, Wc = hC@w2c, fused div+ave message --------
  float* mrow = msg + (long)(e - e0) * 192;
  for (int j4 = 0; j4 < 96; j4 += 4){
    float pv[4], qv[4];
#pragma unroll
    for (int jj = 0; jj < 4; jj++){
      int j = j4 + jj;
      float d1 = 0.f, d2 = 0.f, c1 = 0.f, c2 = 0.f;
      const uint4* r1 = (const uint4*)(dw2 + j*16);
      const uint4* r2 = (const uint4*)(dw2 + (96+j)*16);
#pragma unroll
      for (int q = 0; q < 4; q++){
        uint4 wa = r1[q], wb = r2[q];
        d1 = dot2(wa.x, hdp[q*4+0], d1); d1 = dot2(wa.y, hdp[q*4+1], d1);
        d1 = dot2(wa.z, hdp[q*4+2], d1); d1 = dot2(wa.w, hdp[q*4+3], d1);
        d2 = dot2(wb.x, hdp[q*4+0], d2); d2 = dot2(wb.y, hdp[q*4+1], d2);
        d2 = dot2(wb.z, hdp[q*4+2], d2); d2 = dot2(wb.w, hdp[q*4+3], d2);
      }
      const uint4* r3 = (const uint4*)(w2c + j*32);
      const uint4* r4 = (const uint4*)(w2c + (96+j)*32);
#pragma unroll
      for (int q = 0; q < 8; q++){
        uint4 wa = r3[q], wb = r4[q];
        c1 = dot2(wa.x, hcp[q*4+0], c1); c1 = dot2(wa.y, hcp[q*4+1], c1);
        c1 = dot2(wa.z, hcp[q*4+2], c1); c1 = dot2(wa.w, hcp[q*4+3], c1);
        c2 = dot2(wb.x, hcp[q*4+0], c2); c2 = dot2(wb.y, hcp[q*4+1], c2);
        c2 = dot2(wb.z, hcp[q*4+2], c2); c2 = dot2(wb.w, hcp[q*4+3], c2);
      }
      float dv = 8.f * c1 * d1;          // undo hdp 1/8 scale
      float av = 4.f * c2 * d2;          // 0.5 * 8
      pv[jj] = dv + av;
      qv[jj] = av - dv;
    }
    float4 P, Q;
    P.x = pv[0]; P.y = pv[1]; P.z = pv[2]; P.w = pv[3];
    Q.x = qv[0]; Q.y = qv[1]; Q.z = qv[2]; Q.w = qv[3];
    *(float4*)(mrow + j4)      = P;
    *(float4*)(mrow + 96 + j4) = Q;
  }
}

// one block (128 threads, 96 active) per node; accumulate into delta
__global__ __launch_bounds__(128) void gather_layer(
    const int* __restrict__ inc, const int* __restrict__ off,
    const float* __restrict__ msg, float* __restrict__ delta, int e0, int e1)
{
  int n = blockIdx.x;
  int c = threadIdx.x;
  if (c >= 96) return;
  int i0 = off[n], i1 = off[n+1];
  float acc = 0.f;
  for (int ii = i0; ii < i1; ii++){
    int v = inc[ii];
    int e = v >> 1;
    if (e < e0 || e >= e1) continue;
    acc += msg[(long)(e - e0) * 192 + (v & 1) * 96 + c];
  }
  delta[(long)n * 96 + c] += acc;
}

// ---------------- xn -= h*delta; re-zero delta ------------------------------
__global__ void node_upd(float* __restrict__ xn, float* __restrict__ delta){
  int i = blockIdx.x * 256 + threadIdx.x;
  if (i < NN * 96){
    xn[i] -= 0.1f * delta[i];
    delta[i] = 0.f;
  }
}

// ---------------- column sum over nodes -------------------------------------
__global__ void colsum(const float* __restrict__ xn, float* __restrict__ nodesum){
  int col = threadIdx.x % 96;
  int seg = threadIdx.x / 96;
  int stripe = blockIdx.x * 2 + seg;   // 0..399
  float acc = 0.f;
  for (int n = stripe; n < NN; n += 400) acc += xn[(long)n * 96 + col];
  unsafeAtomicAdd(nodesum + col, acc);
}

// ---------------- project to 16 outputs, scale, fp32 store ------------------
__global__ void project(const float* __restrict__ nodesum, const float* __restrict__ siT,
                        float* __restrict__ out){
  int j = threadIdx.x;
  if (j < 16){
    float a = 0.f;
#pragma unroll
    for (int c = 0; c < 96; c++) a += nodesum[c] * siT[j*96 + c];
    out[j] = a * 0.007071067811865475f;   // 1/sqrt(20000)
  }
}

// ---------------- host side -------------------------------------------------
extern "C" void kernel_launch(void* const* d_in, const int* in_sizes, int n_in,
                              void* d_out, int out_size, void* d_ws, size_t ws_size,
                              hipStream_t stream){
  const float* pos  = (const float*)d_in[0];
  const int* atom_z = (const int*)d_in[1];
  const int* esrc   = (const int*)d_in[2];
  const int* edst   = (const int*)d_in[3];

  float* ws      = (float*)d_ws;
  float* xn      = ws;                  // NN*96 = 1,920,000
  float* delta   = ws + 1920000;        // NN*96
  float* nodesum = ws + 3840000;        // 96
  float* WB      = ws + 3840096;        // 13,344 fp32 weights
  unsigned int* pk = (unsigned int*)(ws + 3853440);  // 2*18432 packed uints
  int*   cnt     = (int*)(ws + 3890304);        // 20,000
  int*   cur     = cnt + 20000;                 // 20,000
  int*   off     = cur + 20000;                 // 20,004 (pad)
  int*   inc     = off + 20004;                 // 640,000
  float* msg     = ws + 4590308;                // rest

  long wsFloats  = (long)(ws_size / 4);
  long msgFloats = wsFloats - 4590308L;
  if (msgFloats < 192 * 1024) msgFloats = 192 * 1024;  // last-resort floor
  long CE  = msgFloats / 192; if (CE > NE) CE = NE;    // layer chunk (192 f/edge)
  long CEi = msgFloats / 64;  if (CEi > NE) CEi = NE;  // init chunk  (64 f/edge)

  float* embedF = WB + 0;        // 160
  float* dl0w1T = WB + 160;      // 256   [32][8]
  float* dl0w2T = WB + 416;      // 1024  [32][32]
  float* dl1w1T = WB + 1440;     // 128   [32][4]
  float* dl1w2T = WB + 1568;     // 1024  [32][32]
  float* f01w1T = WB + 2592;     // 1280  [2][64][10]
  float* f01w2T = WB + 3872;     // 4096  [2][32][64]
  float* wAw1T  = WB + 7968;     // 2560  [2][2][64][10]
  float* wCw1T  = WB + 10528;    // 1280  [2][64][10]
  float* siT    = WB + 11808;    // 1536  [16][96]

  hipMemsetAsync(cnt, 0, 20000 * 4, stream);
  hipMemsetAsync(delta, 0, (size_t)NN * 96 * 4, stream);
  hipMemsetAsync(nodesum, 0, 96 * 4, stream);

  TTab tb;
  int ti = 0;
  auto add = [&](const void* s, float* dst, int R, int C, int tr){
    tb.e[ti].src = (const float*)s; tb.e[ti].dst = dst;
    tb.e[ti].R = R; tb.e[ti].C = C; tb.e[ti].trans = tr; ti++;
  };
  add(d_in[4],  embedF, 20, 8, 0);
  add(d_in[5],  dl0w1T, 8, 32, 1);
  add(d_in[6],  dl0w2T, 32, 32, 1);
  add(d_in[7],  dl1w1T, 4, 32, 1);
  add(d_in[8],  dl1w2T, 32, 32, 1);
  for (int p = 0; p < 2; p++) add((const float*)d_in[9]  + p*640,  f01w1T + p*640,  10, 64, 1);
  for (int p = 0; p < 2; p++) add((const float*)d_in[10] + p*2048, f01w2T + p*2048, 64, 32, 1);
  for (int q = 0; q < 4; q++) add((const float*)d_in[11] + q*640,  wAw1T + q*640,   10, 64, 1);
  for (int i = 0; i < 2; i++) add((const float*)d_in[13] + i*640,  wCw1T + i*640,   10, 64, 1);
  add(d_in[17], siT, 96, 16, 1);

  PTab pt;
  int pi = 0;
  auto padd = [&](const void* s, unsigned int* dst, int R, int C){
    pt.e[pi].src = (const float*)s; pt.e[pi].dst = dst;
    pt.e[pi].R = R; pt.e[pi].C = C; pi++;
  };
  for (int i = 0; i < 2; i++){
    padd((const float*)d_in[12] + (i*2+0)*6144, pk + i*18432 + 0,     64, 96);   // w2a
    padd((const float*)d_in[12] + (i*2+1)*6144, pk + i*18432 + 3072,  64, 96);   // w2b
    padd((const float*)d_in[15] + i*6144,       pk + i*18432 + 6144,  192, 32);  // dw1T
    padd((const float*)d_in[14] + i*12288,      pk + i*18432 + 9216,  64, 192);  // w2c
    padd((const float*)d_in[16] + i*6144,       pk + i*18432 + 15360, 32, 192);  // dw2
  }

  convw<<<16, 256, 0, stream>>>(tb);
  packw<<<10, 256, 0, stream>>>(pt);
  count_k<<<(NE + 255)/256, 256, 0, stream>>>(esrc, edst, cnt);
  prefix_k<<<1, 1024, 0, stream>>>(cnt, off, cur);
  fill_k<<<(NE + 255)/256, 256, 0, stream>>>(esrc, edst, cur, inc);
  node_init<<<(NN + 255)/256, 256, 0, stream>>>(atom_z, embedF, dl0w1T, dl0w2T, xn);

  for (long e0 = 0; e0 < NE; e0 += CEi){
    long e1 = e0 + CEi; if (e1 > NE) e1 = NE;
    edge_init<<<(int)((e1 - e0 + 255)/256), 256, 0, stream>>>(
        pos, esrc, edst, msg, (int)e0, (int)e1, dl1w1T, dl1w2T, f01w1T, f01w2T);
    gather_init<<<NN, 64, 0, stream>>>(inc, off, msg, xn, (int)e0, (int)e1);
  }

  for (int i = 0; i < 2; i++){
    for (long e0 = 0; e0 < NE; e0 += CE){
      long e1 = e0 + CE; if (e1 > NE) e1 = NE;
      layer_k<<<(int)((e1 - e0 + 511)/512), 512, 0, stream>>>(
          pos, esrc, edst, xn, msg, (int)e0, (int)e1,
          wAw1T + (i*2+0)*640, wAw1T + (i*2+1)*640, wCw1T + i*640,
          pk + i*18432);
      gather_layer<<<NN, 128, 0, stream>>>(inc, off, msg, delta, (int)e0, (int)e1);
    }
    node_upd<<<(NN*96 + 255)/256, 256, 0, stream>>>(xn, delta);
  }
  colsum<<<200, 192, 0, stream>>>(xn, nodesum);
  project<<<1, 64, 0, stream>>>(nodesum, siT, (float*)d_out);
}

// Round 7
// 1538.245 us; speedup vs baseline: 6.0627x; 1.0960x over previous
//
#include <hip/hip_runtime.h>
#include <hip/hip_bf16.h>

#define NN 20000
#define NE 320000

typedef _Float16 h2f __attribute__((ext_vector_type(2)));

__device__ __forceinline__ h2f u2h(unsigned int u){
  union { unsigned int u; h2f h; } v; v.u = u; return v.h;
}
__device__ __forceinline__ unsigned int pack2(float a, float b){
  h2f h; h.x = (_Float16)a; h.y = (_Float16)b;
  union { h2f h; unsigned int u; } v; v.h = h; return v.u;
}
__device__ __forceinline__ float dot2(unsigned int w, h2f x, float acc){
#if __has_builtin(__builtin_amdgcn_fdot2)
  return __builtin_amdgcn_fdot2(u2h(w), x, acc, false);
#else
  h2f c = u2h(w);
  return acc + (float)(c.x) * (float)(x.x) + (float)(c.y) * (float)(x.y);
#endif
}

// jax.nn.gelu default (approximate=True): 0.5x(1+tanh(t)) == x*sigmoid(2t)
__device__ __forceinline__ float geluf(float x){
  float t = 0.7978845608028654f * x * (1.0f + 0.044715f * x * x);
  return x / (1.0f + __expf(-2.0f * t));
}

// compute bessel basis b[10] from edge geometry via sin recurrence
__device__ __forceinline__ void edge_geom(const float* __restrict__ pos, int s, int d,
                                          float* b, float* vx, float* vy, float* vz,
                                          float* len, float* inv){
  float x = pos[s*3+0] - pos[d*3+0];
  float y = pos[s*3+1] - pos[d*3+1];
  float z = pos[s*3+2] - pos[d*3+2];
  float L = sqrtf(x*x + y*y + z*z + 1e-12f);
  float iv = 1.0f / fmaxf(L, 1e-6f);
  float th = 1.5707963267948966f * L;        // pi*len/2
  float s1 = sinf(th), c1 = cosf(th);
  float scale = iv * 3.1622776601683795f;    // sqrt(2/MAXR)*sqrt(B)/r
  float sp = 0.f, sc = s1, c2 = 2.0f * c1;
  #pragma unroll
  for (int k = 0; k < 10; k++){
    b[k] = sc * scale;
    float sn = c2 * sc - sp;
    sp = sc; sc = sn;
  }
  *vx = x; *vy = y; *vz = z; *len = L; *inv = iv;
}

// ---------------- weight transpose/copy (fp32 -> fp32 in ws) ----------------
struct TEnt { const float* src; float* dst; int R; int C; int trans; };
struct TTab { TEnt e[16]; };

__global__ void convw(TTab t){
  TEnt en = t.e[blockIdx.x];
  int n = en.R * en.C;
  for (int i = threadIdx.x; i < n; i += blockDim.x){
    float v = en.src[i];
    if (en.trans){
      int r = i / en.C, c = i - r * en.C;
      en.dst[c * en.R + r] = v;          // dst[C][R]
    } else {
      en.dst[i] = v;
    }
  }
}

// ---------------- pack fp32 [R][C] -> f16-pair uints [C][R/2] ---------------
// dst[c*(R/2)+rp] = pack(src[2rp][c], src[2rp+1][c])  (pairs over R)
struct PEnt { const float* src; unsigned int* dst; int R; int C; };
struct PTab { PEnt e[10]; };

__global__ void packw(PTab t){
  PEnt en = t.e[blockIdx.x];
  int half = en.R >> 1;
  int n = en.C * half;
  for (int i = threadIdx.x; i < n; i += blockDim.x){
    int c = i / half, rp = i - c * half;
    float a = en.src[(2*rp)     * en.C + c];
    float b = en.src[(2*rp + 1) * en.C + c];
    en.dst[i] = pack2(a, b);
  }
}

// ---------------- CSR build --------------------------------------------------
__global__ void count_k(const int* __restrict__ esrc, const int* __restrict__ edst,
                        int* __restrict__ cnt){
  int e = blockIdx.x * 256 + threadIdx.x;
  if (e >= NE) return;
  atomicAdd(cnt + edst[e], 1);
  atomicAdd(cnt + esrc[e], 1);
}

__global__ __launch_bounds__(1024) void prefix_k(const int* __restrict__ cnt,
                                                 int* __restrict__ off, int* __restrict__ cur){
  __shared__ int part[1024];
  int t = threadIdx.x;
  int base = t * 20;
  int s = 0;
  for (int i = 0; i < 20; i++){ int idx = base + i; if (idx < NN) s += cnt[idx]; }
  part[t] = s; __syncthreads();
  for (int d = 1; d < 1024; d <<= 1){
    int v = (t >= d) ? part[t - d] : 0;
    __syncthreads();
    part[t] += v;
    __syncthreads();
  }
  int run = (t == 0) ? 0 : part[t - 1];
  for (int i = 0; i < 20; i++){
    int idx = base + i;
    if (idx < NN){ off[idx] = run; cur[idx] = run; run += cnt[idx]; }
  }
  if (t == 0) off[NN] = 2 * NE;
}

__global__ void fill_k(const int* __restrict__ esrc, const int* __restrict__ edst,
                       int* __restrict__ cur, int* __restrict__ inc){
  int e = blockIdx.x * 256 + threadIdx.x;
  if (e >= NE) return;
  int pd = atomicAdd(cur + edst[e], 1);
  inc[pd] = (e << 1);          // role 0: this node is dst
  int ps = atomicAdd(cur + esrc[e], 1);
  inc[ps] = (e << 1) | 1;      // role 1: this node is src
}

// ---------------- node init: xn[:,0:32] = mlp2(embed[z]), zero rest ---------
__global__ __launch_bounds__(256) void node_init(
    const int* __restrict__ az, const float* __restrict__ embedF,
    const float* __restrict__ w1T /*[32][8]*/, const float* __restrict__ w2T /*[32][32]*/,
    float* __restrict__ xn)
{
  int n = blockIdx.x * 256 + threadIdx.x;
  if (n >= NN) return;
  int z = az[n];
  float ee[8];
#pragma unroll
  for (int k = 0; k < 8; k++) ee[k] = embedF[z * 8 + k];
  float hid[32];
#pragma unroll
  for (int l = 0; l < 32; l++){
    float a = 0.f;
#pragma unroll
    for (int k = 0; k < 8; k++) a += ee[k] * w1T[l * 8 + k];
    hid[l] = geluf(a);
  }
  float* row = xn + (long)n * 96;
#pragma unroll
  for (int j = 0; j < 32; j++){
    float a = 0.f;
#pragma unroll
    for (int l = 0; l < 32; l++) a += hid[l] * w2T[j * 32 + l];
    row[j] = a;
  }
#pragma unroll
  for (int j = 32; j < 96; j++) row[j] = 0.f;
}

// ---------------- edge init: per-edge f16 messages (64 halves = 128B) -------
// msg[e-e0][0:32]  = W0 * xeh        (div payload, sign applied gather-side)
// msg[e-e0][32:64] = 0.5 * W1 * xeh  (ave payload)
__global__ __launch_bounds__(256) void edge_init(
    const float* __restrict__ pos, const int* __restrict__ esrc, const int* __restrict__ edst,
    unsigned short* __restrict__ msgh, int e0, int e1,
    const float* __restrict__ w1T /*dl1w1T [32][4]*/, const float* __restrict__ w2T /*[32][32]*/,
    const float* __restrict__ f1T /*[2][64][10]*/, const float* __restrict__ f2T /*[2][32][64]*/)
{
  int e = e0 + blockIdx.x * 256 + threadIdx.x;
  if (e >= e1) return;
  int s = esrc[e], d = edst[e];
  float b[10], vx, vy, vz, len, inv;
  edge_geom(pos, s, d, b, &vx, &vy, &vz, &len, &inv);

  float u = len - 2.0f;   // 2*(len/MAXR - 1), MAXR=2
  float cut = 0.5f * (1.0f - cosf(3.14159265358979323f * u));
  cut = (u > 0.0f) ? 0.0f : cut;
  cut = (u < -1.0f) ? 1.0f : cut;
  float xe0 = cut, cc = cut * 1.7320508075688772f * inv;
  float xe1 = cc*vx, xe2 = cc*vy, xe3 = cc*vz;
  float hid[32];
#pragma unroll
  for (int l = 0; l < 32; l++){
    float a = xe0*w1T[l*4+0] + xe1*w1T[l*4+1] + xe2*w1T[l*4+2] + xe3*w1T[l*4+3];
    hid[l] = geluf(a);
  }
  float xeh[32];
#pragma unroll
  for (int j = 0; j < 32; j++){
    float a = 0.f;
#pragma unroll
    for (int l = 0; l < 32; l++) a += hid[l] * w2T[j*32 + l];
    xeh[j] = a;
  }
  unsigned short* mrow = msgh + (long)(e - e0) * 64;
  float h64[64];
#pragma unroll
  for (int l = 0; l < 64; l++){
    float a = 0.f;
#pragma unroll
    for (int k = 0; k < 10; k++) a += b[k] * f1T[l*10 + k];
    h64[l] = geluf(a);
  }
  {
    unsigned int du[16];
#pragma unroll
    for (int jp = 0; jp < 16; jp++){
      float v2[2];
#pragma unroll
      for (int w = 0; w < 2; w++){
        int j = 2*jp + w;
        float a = 0.f;
#pragma unroll
        for (int l = 0; l < 64; l++) a += h64[l] * f2T[j*64 + l];
        v2[w] = a * xeh[j] * 0.0625f;     // store true/16
      }
      du[jp] = pack2(v2[0], v2[1]);
    }
    uint4* dd = (uint4*)mrow;             // bytes [0,64): one full line
#pragma unroll
    for (int q = 0; q < 4; q++) dd[q] = ((uint4*)du)[q];
  }
#pragma unroll
  for (int l = 0; l < 64; l++){
    float a = 0.f;
#pragma unroll
    for (int k = 0; k < 10; k++) a += b[k] * f1T[640 + l*10 + k];
    h64[l] = geluf(a);
  }
  {
    unsigned int au[16];
#pragma unroll
    for (int jp = 0; jp < 16; jp++){
      float v2[2];
#pragma unroll
      for (int w = 0; w < 2; w++){
        int j = 2*jp + w;
        float a = 0.f;
#pragma unroll
        for (int l = 0; l < 64; l++) a += h64[l] * f2T[2048 + j*64 + l];
        v2[w] = 0.5f * a * xeh[j] * 0.0625f;   // store true/16
      }
      au[jp] = pack2(v2[0], v2[1]);
    }
    uint4* dd = (uint4*)(mrow + 32);      // bytes [64,128): one full line
#pragma unroll
    for (int q = 0; q < 4; q++) dd[q] = ((uint4*)au)[q];
  }
}

// one block (64 threads) per node; cols 32..95 of xn accumulate
__global__ __launch_bounds__(64) void gather_init(
    const int* __restrict__ inc, const int* __restrict__ off,
    const unsigned short* __restrict__ msgh, float* __restrict__ xn, int e0, int e1)
{
  int n = blockIdx.x;
  int c = threadIdx.x;          // 0..63
  int i0 = off[n], i1 = off[n+1];
  const _Float16* mh = (const _Float16*)msgh;
  float acc = 0.f;
  for (int ii = i0; ii < i1; ii++){
    int v = inc[ii];
    int e = v >> 1;
    if (e < e0 || e >= e1) continue;
    float m = (float)mh[(long)(e - e0) * 64 + c];
    // first 32 cols: div payload, src side negates; last 32: ave payload
    float sgn = (c < 32 && (v & 1)) ? -1.0f : 1.0f;
    acc += sgn * m;
  }
  xn[(long)n * 96 + 32 + c] += 16.f * acc;   // undo 1/16 msg scale
}

// ---------------- conv layer: f16-dot2 with LDS-staged weights --------------
// msg row = 192 f16 halves (384B): p=[0,96) by dst, q=[96,192) by src
// stored value = true/64 (undone in gather_layer)
// pk layout (uints): w2a[96][32] @0, w2b[96][32] @3072, dw1T[32][96] @6144,
//                    w2c[192][32] @9216, dw2[192][16] @15360   (total 18432)
__global__ __launch_bounds__(512, 4) void layer_k(
    const float* __restrict__ pos, const int* __restrict__ esrc,
    const int* __restrict__ edst, const float* __restrict__ xn,
    unsigned short* __restrict__ msgh, int e0, int e1,
    const float* __restrict__ w1aT, const float* __restrict__ w1bT,
    const float* __restrict__ w1cT, const unsigned int* __restrict__ pk)
{
  __shared__ uint4 lw4[4608];          // 72 KB packed-f16 weights
  unsigned int* lw = (unsigned int*)lw4;
  int t = threadIdx.x;
  {
    const uint4* s4 = (const uint4*)pk;
    for (int i = t; i < 4608; i += 512) lw4[i] = s4[i];
  }
  __syncthreads();
  int e = e0 + blockIdx.x * 512 + t;
  if (e >= e1) return;

  const unsigned int* w2a  = lw;
  const unsigned int* w2b  = lw + 3072;
  const unsigned int* dw1T = lw + 6144;
  const unsigned int* w2c  = lw + 9216;
  const unsigned int* dw2  = lw + 15360;

  int s = esrc[e], d = edst[e];
  float b10[10], vx, vy, vz, len, inv;
  edge_geom(pos, s, d, b10, &vx, &vy, &vz, &len, &inv);
  const float* xsr = xn + (long)s * 96;
  const float* xdr = xn + (long)d * 96;

  float hd[32];
#pragma unroll
  for (int l = 0; l < 32; l++) hd[l] = 0.f;

  // ---- passes A (grad) and B (ave): hd += dlL_w1^T @ (W*(x combo)) --------
  // gg packed at 1/32 scale -> hd holds true/32
#pragma unroll 1
  for (int pp = 0; pp < 2; pp++){
    const float* w1 = pp ? w1bT : w1aT;
    const unsigned int* w2 = pp ? w2b : w2a;
    int jbase = pp ? 48 : 0;   // dw1T pair-column offset (j in [96,192))

    h2f hp[32];
#pragma unroll
    for (int lp = 0; lp < 32; lp++){
      float a0 = 0.f, a1 = 0.f;
#pragma unroll
      for (int k = 0; k < 10; k++){
        a0 += b10[k] * w1[(2*lp)  *10 + k];
        a1 += b10[k] * w1[(2*lp+1)*10 + k];
      }
      h2f r; r.x = (_Float16)geluf(a0); r.y = (_Float16)geluf(a1);
      hp[lp] = r;
    }

    for (int jc = 0; jc < 96; jc += 8){
      float4 t0 = *(const float4*)(xsr + jc);
      float4 t1 = *(const float4*)(xsr + jc + 4);
      float4 u0 = *(const float4*)(xdr + jc);
      float4 u1 = *(const float4*)(xdr + jc + 4);
      float xs[8] = {t0.x,t0.y,t0.z,t0.w,t1.x,t1.y,t1.z,t1.w};
      float xd[8] = {u0.x,u0.y,u0.z,u0.w,u1.x,u1.y,u1.z,u1.w};

      h2f gp[4];
#pragma unroll
      for (int p = 0; p < 4; p++){
        float gg[2];
#pragma unroll
        for (int w = 0; w < 2; w++){
          int j = jc + 2*p + w;
          const uint4* wr = (const uint4*)(w2 + j*32);
          float a = 0.f;
#pragma unroll
          for (int q = 0; q < 8; q++){
            uint4 ww = wr[q];
            a = dot2(ww.x, hp[q*4+0], a);
            a = dot2(ww.y, hp[q*4+1], a);
            a = dot2(ww.z, hp[q*4+2], a);
            a = dot2(ww.w, hp[q*4+3], a);
          }
          float xv = pp ? 0.5f*(xd[2*p+w] + xs[2*p+w]) : (xd[2*p+w] - xs[2*p+w]);
          gg[w] = a * xv * 0.03125f;     // 1/32 scale for f16 range
        }
        h2f r; r.x = (_Float16)gg[0]; r.y = (_Float16)gg[1];
        gp[p] = r;
      }
      int jp0 = jbase + (jc >> 1);
#pragma unroll
      for (int l = 0; l < 32; l++){
        uint4 ww = *(const uint4*)(dw1T + l*96 + jp0);
        float acc = hd[l];
        acc = dot2(ww.x, gp[0], acc);
        acc = dot2(ww.y, gp[1], acc);
        acc = dot2(ww.z, gp[2], acc);
        acc = dot2(ww.w, gp[3], acc);
        hd[l] = acc;
      }
    }
  }

  // ---- hd gelu (undo 1/32), pack at 1/64 for output dots ----
  h2f hdp[16];
#pragma unroll
  for (int lp = 0; lp < 16; lp++){
    h2f r;
    r.x = (_Float16)(geluf(32.f*hd[2*lp])   * 0.015625f);
    r.y = (_Float16)(geluf(32.f*hd[2*lp+1]) * 0.015625f);
    hdp[lp] = r;
  }
  // ---- hC ----
  h2f hcp[32];
#pragma unroll
  for (int lp = 0; lp < 32; lp++){
    float a0 = 0.f, a1 = 0.f;
#pragma unroll
    for (int k = 0; k < 10; k++){
      a0 += b10[k] * w1cT[(2*lp)  *10 + k];
      a1 += b10[k] * w1cT[(2*lp+1)*10 + k];
    }
    h2f r; r.x = (_Float16)geluf(a0); r.y = (_Float16)geluf(a1);
    hcp[lp] = r;
  }

  // ---- output: 32-col chunks, pack f16 at true/64, full-line stores -------
  // dv_true = 64*c1*d1 (hdp at 1/64); stored = dv_true/64 = c1*d1
  // av_true = 0.5*64*c2*d2;          stored = 0.5*c2*d2
  unsigned short* mrow = msgh + (long)(e - e0) * 192;   // 384B row, 64B aligned
  for (int c0 = 0; c0 < 96; c0 += 32){
    unsigned int pu[16], qu[16];
#pragma unroll
    for (int jp = 0; jp < 16; jp++){
      float pv2[2], qv2[2];
#pragma unroll
      for (int w = 0; w < 2; w++){
        int j = c0 + 2*jp + w;
        float d1 = 0.f, d2 = 0.f, c1 = 0.f, c2 = 0.f;
        const uint4* r1 = (const uint4*)(dw2 + j*16);
        const uint4* r2 = (const uint4*)(dw2 + (96+j)*16);
#pragma unroll
        for (int q = 0; q < 4; q++){
          uint4 wa = r1[q], wb = r2[q];
          d1 = dot2(wa.x, hdp[q*4+0], d1); d1 = dot2(wa.y, hdp[q*4+1], d1);
          d1 = dot2(wa.z, hdp[q*4+2], d1); d1 = dot2(wa.w, hdp[q*4+3], d1);
          d2 = dot2(wb.x, hdp[q*4+0], d2); d2 = dot2(wb.y, hdp[q*4+1], d2);
          d2 = dot2(wb.z, hdp[q*4+2], d2); d2 = dot2(wb.w, hdp[q*4+3], d2);
        }
        const uint4* r3 = (const uint4*)(w2c + j*32);
        const uint4* r4 = (const uint4*)(w2c + (96+j)*32);
#pragma unroll
        for (int q = 0; q < 8; q++){
          uint4 wa = r3[q], wb = r4[q];
          c1 = dot2(wa.x, hcp[q*4+0], c1); c1 = dot2(wa.y, hcp[q*4+1], c1);
          c1 = dot2(wa.z, hcp[q*4+2], c1); c1 = dot2(wa.w, hcp[q*4+3], c1);
          c2 = dot2(wb.x, hcp[q*4+0], c2); c2 = dot2(wb.y, hcp[q*4+1], c2);
          c2 = dot2(wb.z, hcp[q*4+2], c2); c2 = dot2(wb.w, hcp[q*4+3], c2);
        }
        float dv = c1 * d1;           // true/64
        float av = 0.5f * c2 * d2;    // true/64
        pv2[w] = dv + av;
        qv2[w] = av - dv;
      }
      pu[jp] = pack2(pv2[0], pv2[1]);
      qu[jp] = pack2(qv2[0], qv2[1]);
    }
    uint4* pd = (uint4*)(mrow + c0);        // line-aligned full 64B
    uint4* qd = (uint4*)(mrow + 96 + c0);   // line-aligned full 64B
#pragma unroll
    for (int q = 0; q < 4; q++){
      pd[q] = ((uint4*)pu)[q];
      qd[q] = ((uint4*)qu)[q];
    }
  }
}

// one block (128 threads, 96 active) per node; accumulate into delta
__global__ __launch_bounds__(128) void gather_layer(
    const int* __restrict__ inc, const int* __restrict__ off,
    const unsigned short* __restrict__ msgh, float* __restrict__ delta, int e0, int e1)
{
  int n = blockIdx.x;
  int c = threadIdx.x;
  if (c >= 96) return;
  int i0 = off[n], i1 = off[n+1];
  const _Float16* mh = (const _Float16*)msgh;
  float acc = 0.f;
  for (int ii = i0; ii < i1; ii++){
    int v = inc[ii];
    int e = v >> 1;
    if (e < e0 || e >= e1) continue;
    acc += (float)mh[(long)(e - e0) * 192 + (v & 1) * 96 + c];
  }
  delta[(long)n * 96 + c] += 64.f * acc;   // undo 1/64 msg scale
}

// ---------------- xn -= h*delta; re-zero delta ------------------------------
__global__ void node_upd(float* __restrict__ xn, float* __restrict__ delta){
  int i = blockIdx.x * 256 + threadIdx.x;
  if (i < NN * 96){
    xn[i] -= 0.1f * delta[i];
    delta[i] = 0.f;
  }
}

// ---------------- column sum over nodes -------------------------------------
__global__ void colsum(const float* __restrict__ xn, float* __restrict__ nodesum){
  int col = threadIdx.x % 96;
  int seg = threadIdx.x / 96;
  int stripe = blockIdx.x * 2 + seg;   // 0..399
  float acc = 0.f;
  for (int n = stripe; n < NN; n += 400) acc += xn[(long)n * 96 + col];
  unsafeAtomicAdd(nodesum + col, acc);
}

// ---------------- project to 16 outputs, scale, fp32 store ------------------
__global__ void project(const float* __restrict__ nodesum, const float* __restrict__ siT,
                        float* __restrict__ out){
  int j = threadIdx.x;
  if (j < 16){
    float a = 0.f;
#pragma unroll
    for (int c = 0; c < 96; c++) a += nodesum[c] * siT[j*96 + c];
    out[j] = a * 0.007071067811865475f;   // 1/sqrt(20000)
  }
}

// ---------------- host side -------------------------------------------------
extern "C" void kernel_launch(void* const* d_in, const int* in_sizes, int n_in,
                              void* d_out, int out_size, void* d_ws, size_t ws_size,
                              hipStream_t stream){
  const float* pos  = (const float*)d_in[0];
  const int* atom_z = (const int*)d_in[1];
  const int* esrc   = (const int*)d_in[2];
  const int* edst   = (const int*)d_in[3];

  float* ws      = (float*)d_ws;
  float* xn      = ws;                  // NN*96 = 1,920,000
  float* delta   = ws + 1920000;        // NN*96
  float* nodesum = ws + 3840000;        // 96
  float* WB      = ws + 3840096;        // 13,344 fp32 weights
  unsigned int* pk = (unsigned int*)(ws + 3853440);  // 2*18432 packed uints
  int*   cnt     = (int*)(ws + 3890304);        // 20,000
  int*   cur     = cnt + 20000;                 // 20,000
  int*   off     = cur + 20000;                 // 20,004 (pad)
  int*   inc     = off + 20004;                 // 640,000
  unsigned short* msgh = (unsigned short*)(ws + 4590320);  // 64B-aligned f16 msgs

  long wsFloats  = (long)(ws_size / 4);
  long msgHalves = (wsFloats - 4590320L) * 2;
  if (msgHalves < 192 * 1024) msgHalves = 192 * 1024;  // last-resort floor
  long CE  = msgHalves / 192; if (CE > NE) CE = NE;    // layer chunk (192 h/edge)
  long CEi = msgHalves / 64;  if (CEi > NE) CEi = NE;  // init chunk  (64 h/edge)

  float* embedF = WB + 0;        // 160
  float* dl0w1T = WB + 160;      // 256   [32][8]
  float* dl0w2T = WB + 416;      // 1024  [32][32]
  float* dl1w1T = WB + 1440;     // 128   [32][4]
  float* dl1w2T = WB + 1568;     // 1024  [32][32]
  float* f01w1T = WB + 2592;     // 1280  [2][64][10]
  float* f01w2T = WB + 3872;     // 4096  [2][32][64]
  float* wAw1T  = WB + 7968;     // 2560  [2][2][64][10]
  float* wCw1T  = WB + 10528;    // 1280  [2][64][10]
  float* siT    = WB + 11808;    // 1536  [16][96]

  hipMemsetAsync(cnt, 0, 20000 * 4, stream);
  hipMemsetAsync(delta, 0, (size_t)NN * 96 * 4, stream);
  hipMemsetAsync(nodesum, 0, 96 * 4, stream);

  TTab tb;
  int ti = 0;
  auto add = [&](const void* s, float* dst, int R, int C, int tr){
    tb.e[ti].src = (const float*)s; tb.e[ti].dst = dst;
    tb.e[ti].R = R; tb.e[ti].C = C; tb.e[ti].trans = tr; ti++;
  };
  add(d_in[4],  embedF, 20, 8, 0);
  add(d_in[5],  dl0w1T, 8, 32, 1);
  add(d_in[6],  dl0w2T, 32, 32, 1);
  add(d_in[7],  dl1w1T, 4, 32, 1);
  add(d_in[8],  dl1w2T, 32, 32, 1);
  for (int p = 0; p < 2; p++) add((const float*)d_in[9]  + p*640,  f01w1T + p*640,  10, 64, 1);
  for (int p = 0; p < 2; p++) add((const float*)d_in[10] + p*2048, f01w2T + p*2048, 64, 32, 1);
  for (int q = 0; q < 4; q++) add((const float*)d_in[11] + q*640,  wAw1T + q*640,   10, 64, 1);
  for (int i = 0; i < 2; i++) add((const float*)d_in[13] + i*640,  wCw1T + i*640,   10, 64, 1);
  add(d_in[17], siT, 96, 16, 1);

  PTab pt;
  int pi = 0;
  auto padd = [&](const void* s, unsigned int* dst, int R, int C){
    pt.e[pi].src = (const float*)s; pt.e[pi].dst = dst;
    pt.e[pi].R = R; pt.e[pi].C = C; pi++;
  };
  for (int i = 0; i < 2; i++){
    padd((const float*)d_in[12] + (i*2+0)*6144, pk + i*18432 + 0,     64, 96);   // w2a
    padd((const float*)d_in[12] + (i*2+1)*6144, pk + i*18432 + 3072,  64, 96);   // w2b
    padd((const float*)d_in[15] + i*6144,       pk + i*18432 + 6144,  192, 32);  // dw1T
    padd((const float*)d_in[14] + i*12288,      pk + i*18432 + 9216,  64, 192);  // w2c
    padd((const float*)d_in[16] + i*6144,       pk + i*18432 + 15360, 32, 192);  // dw2
  }

  convw<<<16, 256, 0, stream>>>(tb);
  packw<<<10, 256, 0, stream>>>(pt);
  count_k<<<(NE + 255)/256, 256, 0, stream>>>(esrc, edst, cnt);
  prefix_k<<<1, 1024, 0, stream>>>(cnt, off, cur);
  fill_k<<<(NE + 255)/256, 256, 0, stream>>>(esrc, edst, cur, inc);
  node_init<<<(NN + 255)/256, 256, 0, stream>>>(atom_z, embedF, dl0w1T, dl0w2T, xn);

  for (long e0 = 0; e0 < NE; e0 += CEi){
    long e1 = e0 + CEi; if (e1 > NE) e1 = NE;
    edge_init<<<(int)((e1 - e0 + 255)/256), 256, 0, stream>>>(
        pos, esrc, edst, msgh, (int)e0, (int)e1, dl1w1T, dl1w2T, f01w1T, f01w2T);
    gather_init<<<NN, 64, 0, stream>>>(inc, off, msgh, xn, (int)e0, (int)e1);
  }

  for (int i = 0; i < 2; i++){
    for (long e0 = 0; e0 < NE; e0 += CE){
      long e1 = e0 + CE; if (e1 > NE) e1 = NE;
      layer_k<<<(int)((e1 - e0 + 511)/512), 512, 0, stream>>>(
          pos, esrc, edst, xn, msgh, (int)e0, (int)e1,
          wAw1T + (i*2+0)*640, wAw1T + (i*2+1)*640, wCw1T + i*640,
          pk + i*18432);
      gather_layer<<<NN, 128, 0, stream>>>(inc, off, msgh, delta, (int)e0, (int)e1);
    }
    node_upd<<<(NN*96 + 255)/256, 256, 0, stream>>>(xn, delta);
  }
  colsum<<<200, 192, 0, stream>>>(xn, nodesum);
  project<<<1, 64, 0, stream>>>(nodesum, siT, (float*)d_out);
}